// Round 1
// baseline (553.784 us; speedup 1.0000x reference)
//
#include <hip/hip_runtime.h>
#include <math.h>

// Sizes (hard-coded per reference): B=1, L=256, D=128, H=4, DH=32
// positions P = L*L = 65536; HD = H*DH = 128
#define NPOS 65536

// ---------------------------------------------------------------------------
// Kernel A: LayerNorm + projections (q,k,v,g) + bias (transposed store)
// grid 1024 x 256 threads; each block handles 64 positions (rows).
// LDS: xn[64][140] (35840 B) + wl[64][64] (16384 B) + wbl[512] (2048 B) = 54272 B
// ---------------------------------------------------------------------------
__global__ __launch_bounds__(256) void ln_proj_kernel(
    const float* __restrict__ pair, const float* __restrict__ ln_w, const float* __restrict__ ln_b,
    const float* __restrict__ Wq, const float* __restrict__ Wk, const float* __restrict__ Wv,
    const float* __restrict__ Wb, const float* __restrict__ Wg, const float* __restrict__ bg,
    float* __restrict__ q, float* __restrict__ k, float* __restrict__ v,
    float* __restrict__ g, float* __restrict__ bias_t)
{
    __shared__ float xn[64][140];   // pad 140: 16B-aligned rows, 2-way-max bank aliasing
    __shared__ float wl[64][64];    // K-half x 64-col weight tile
    __shared__ float wbl[512];      // Wb (128x4)

    const int tid = threadIdx.x;
    const int p0  = blockIdx.x * 64;

    // ---- load pair rows into LDS (float4, coalesced) ----
    for (int i = tid; i < 64 * 32; i += 256) {
        int row = i >> 5, c4 = (i & 31) * 4;
        float4 val = *(const float4*)(pair + (size_t)(p0 + row) * 128 + c4);
        xn[row][c4 + 0] = val.x; xn[row][c4 + 1] = val.y;
        xn[row][c4 + 2] = val.z; xn[row][c4 + 3] = val.w;
    }
    wbl[tid]       = Wb[tid];
    wbl[tid + 256] = Wb[tid + 256];
    __syncthreads();

    // ---- LayerNorm: 4 threads per row, interleaved columns c = s + 4*ii ----
    {
        int r = tid >> 2, s = tid & 3;
        float sum = 0.f, sq = 0.f;
        #pragma unroll
        for (int ii = 0; ii < 32; ++ii) {
            float x = xn[r][s + ii * 4];
            sum += x; sq += x * x;
        }
        sum += __shfl_xor(sum, 1); sq += __shfl_xor(sq, 1);
        sum += __shfl_xor(sum, 2); sq += __shfl_xor(sq, 2);
        float mean = sum * (1.f / 128.f);
        float var  = sq * (1.f / 128.f) - mean * mean;
        float rstd = rsqrtf(var + 1e-5f);
        #pragma unroll
        for (int ii = 0; ii < 32; ++ii) {
            int c = s + ii * 4;
            xn[r][c] = (xn[r][c] - mean) * rstd * ln_w[c] + ln_b[c];
        }
    }
    __syncthreads();

    // ---- bias: one (row,h) per thread; store transposed bias_t[h][k][j] ----
    {
        int rr = tid >> 2, h = tid & 3;
        float dot = 0.f;
        #pragma unroll 8
        for (int kk = 0; kk < 128; ++kk) dot += xn[rr][kk] * wbl[kk * 4 + h];
        int p = p0 + rr;
        int a = p >> 8, bb = p & 255;         // p = (j, k) position
        bias_t[h * NPOS + bb * 256 + a] = dot;
    }

    // ---- main GEMM: 8 chunks of 64 cols (q|k|v|g), K split into 2 halves ----
    const int ty = tid >> 4, tx = tid & 15;   // 16x16 threads -> 4x4 microtile
    const float scale = 0.17677669529663687f; // 1/sqrt(32)

    for (int chunk = 0; chunk < 8; ++chunk) {
        int m = chunk >> 1, col0 = (chunk & 1) * 64;
        const float* W; float* dstp;
        if      (m == 0) { W = Wq; dstp = q; }
        else if (m == 1) { W = Wk; dstp = k; }
        else if (m == 2) { W = Wv; dstp = v; }
        else             { W = Wg; dstp = g; }

        float acc[4][4] = {};
        for (int khalf = 0; khalf < 2; ++khalf) {
            __syncthreads();
            for (int i = tid; i < 64 * 16; i += 256) {
                int row = i >> 4, c4 = (i & 15) * 4;
                *(float4*)&wl[row][c4] =
                    *(const float4*)(W + (khalf * 64 + row) * 128 + col0 + c4);
            }
            __syncthreads();
            int kbase = khalf * 64;
            #pragma unroll 4
            for (int kk = 0; kk < 64; kk += 4) {
                float4 w0 = *(const float4*)&wl[kk + 0][tx * 4];
                float4 w1 = *(const float4*)&wl[kk + 1][tx * 4];
                float4 w2 = *(const float4*)&wl[kk + 2][tx * 4];
                float4 w3 = *(const float4*)&wl[kk + 3][tx * 4];
                #pragma unroll
                for (int rr = 0; rr < 4; ++rr) {
                    float4 av = *(const float4*)&xn[ty * 4 + rr][kbase + kk];
                    acc[rr][0] = fmaf(av.x, w0.x, fmaf(av.y, w1.x, fmaf(av.z, w2.x, fmaf(av.w, w3.x, acc[rr][0]))));
                    acc[rr][1] = fmaf(av.x, w0.y, fmaf(av.y, w1.y, fmaf(av.z, w2.y, fmaf(av.w, w3.y, acc[rr][1]))));
                    acc[rr][2] = fmaf(av.x, w0.z, fmaf(av.y, w1.z, fmaf(av.z, w2.z, fmaf(av.w, w3.z, acc[rr][2]))));
                    acc[rr][3] = fmaf(av.x, w0.w, fmaf(av.y, w1.w, fmaf(av.z, w2.w, fmaf(av.w, w3.w, acc[rr][3]))));
                }
            }
        }
        // epilogue: q-scale / g-sigmoid, store float4
        #pragma unroll
        for (int rr = 0; rr < 4; ++rr) {
            float ov[4];
            #pragma unroll
            for (int c = 0; c < 4; ++c) {
                float val = acc[rr][c];
                if (m == 0) val *= scale;
                if (m == 3) {
                    val += bg[col0 + tx * 4 + c];
                    val = 1.f / (1.f + __expf(-val));
                }
                ov[c] = val;
            }
            *(float4*)(dstp + (size_t)(p0 + ty * 4 + rr) * 128 + col0 + tx * 4) = *(float4*)ov;
        }
    }
}

// ---------------------------------------------------------------------------
// Kernel B: triangle attention, one block per (i,h), one thread per query j.
// K,V staged transposed in LDS [d][k] (64 KB exact): conflict-free writes,
// broadcast reads (k-loop is wave-uniform). Chunked (C=8) online softmax.
// Gate fused into epilogue.
// ---------------------------------------------------------------------------
__global__ __launch_bounds__(256) void attn_kernel(
    const float* __restrict__ q, const float* __restrict__ k, const float* __restrict__ v,
    const float* __restrict__ g, const float* __restrict__ bias_t, float* __restrict__ go)
{
    __shared__ float Kl[32][256];
    __shared__ float Vl[32][256];

    const int tid = threadIdx.x;
    const int i = blockIdx.x >> 2, h = blockIdx.x & 3;
    const size_t base = (size_t)i * 256 * 128 + h * 32;

    // stage K,V (transposed): thread t loads row t, scatters per-d
    {
        const float* kr = k + base + (size_t)tid * 128;
        const float* vr = v + base + (size_t)tid * 128;
        #pragma unroll
        for (int d4 = 0; d4 < 8; ++d4) {
            float4 kv = *(const float4*)(kr + d4 * 4);
            float4 vv = *(const float4*)(vr + d4 * 4);
            Kl[d4 * 4 + 0][tid] = kv.x; Kl[d4 * 4 + 1][tid] = kv.y;
            Kl[d4 * 4 + 2][tid] = kv.z; Kl[d4 * 4 + 3][tid] = kv.w;
            Vl[d4 * 4 + 0][tid] = vv.x; Vl[d4 * 4 + 1][tid] = vv.y;
            Vl[d4 * 4 + 2][tid] = vv.z; Vl[d4 * 4 + 3][tid] = vv.w;
        }
    }
    __syncthreads();

    float q_r[32];
    {
        const float* qr = q + base + (size_t)tid * 128;
        #pragma unroll
        for (int d4 = 0; d4 < 8; ++d4) {
            float4 qv = *(const float4*)(qr + d4 * 4);
            q_r[d4 * 4 + 0] = qv.x; q_r[d4 * 4 + 1] = qv.y;
            q_r[d4 * 4 + 2] = qv.z; q_r[d4 * 4 + 3] = qv.w;
        }
    }

    float m = -1e30f, l = 0.f;
    float acc[32] = {};
    const float* bt = bias_t + h * NPOS + tid;   // bias_t[h][kpos][j=tid]

    for (int k0 = 0; k0 < 256; k0 += 8) {
        float s_r[8];
        float cm = m;
        #pragma unroll
        for (int kk = 0; kk < 8; ++kk) {
            float s = bt[(k0 + kk) * 256];
            #pragma unroll
            for (int d = 0; d < 32; ++d) s = fmaf(q_r[d], Kl[d][k0 + kk], s);
            s_r[kk] = s;
            cm = fmaxf(cm, s);
        }
        float sc = __expf(m - cm);
        m = cm;
        l *= sc;
        #pragma unroll
        for (int d = 0; d < 32; ++d) acc[d] *= sc;
        #pragma unroll
        for (int kk = 0; kk < 8; ++kk) {
            float p = __expf(s_r[kk] - m);
            l += p;
            #pragma unroll
            for (int d = 0; d < 32; ++d) acc[d] = fmaf(p, Vl[d][k0 + kk], acc[d]);
        }
    }

    float inv = 1.f / l;
    const float* gr = g + base + (size_t)tid * 128;
    float* gor      = go + base + (size_t)tid * 128;
    #pragma unroll
    for (int d4 = 0; d4 < 8; ++d4) {
        float4 gv = *(const float4*)(gr + d4 * 4);
        float ov[4];
        ov[0] = acc[d4 * 4 + 0] * inv * gv.x;
        ov[1] = acc[d4 * 4 + 1] * inv * gv.y;
        ov[2] = acc[d4 * 4 + 2] * inv * gv.z;
        ov[3] = acc[d4 * 4 + 3] * inv * gv.w;
        *(float4*)(gor + d4 * 4) = *(float4*)ov;
    }
}

// ---------------------------------------------------------------------------
// Kernel C: out = go @ Wo + bo.  64 rows/block; A-tile in LDS, Wo via L1/L2.
// ---------------------------------------------------------------------------
__global__ __launch_bounds__(256) void out_proj_kernel(
    const float* __restrict__ go, const float* __restrict__ Wo, const float* __restrict__ bo,
    float* __restrict__ out)
{
    __shared__ float at[64][140];
    const int tid = threadIdx.x;
    const int p0  = blockIdx.x * 64;

    for (int i = tid; i < 64 * 32; i += 256) {
        int row = i >> 5, c4 = (i & 31) * 4;
        float4 val = *(const float4*)(go + (size_t)(p0 + row) * 128 + c4);
        at[row][c4 + 0] = val.x; at[row][c4 + 1] = val.y;
        at[row][c4 + 2] = val.z; at[row][c4 + 3] = val.w;
    }
    __syncthreads();

    const int ty = tid >> 4, tx = tid & 15;   // 4 rows x 8 cols per thread
    float acc[4][8] = {};
    #pragma unroll 2
    for (int kk = 0; kk < 128; ++kk) {
        float4 wA = *(const float4*)(Wo + kk * 128 + tx * 8);
        float4 wB = *(const float4*)(Wo + kk * 128 + tx * 8 + 4);
        #pragma unroll
        for (int rr = 0; rr < 4; ++rr) {
            float av = at[ty * 4 + rr][kk];
            acc[rr][0] = fmaf(av, wA.x, acc[rr][0]);
            acc[rr][1] = fmaf(av, wA.y, acc[rr][1]);
            acc[rr][2] = fmaf(av, wA.z, acc[rr][2]);
            acc[rr][3] = fmaf(av, wA.w, acc[rr][3]);
            acc[rr][4] = fmaf(av, wB.x, acc[rr][4]);
            acc[rr][5] = fmaf(av, wB.y, acc[rr][5]);
            acc[rr][6] = fmaf(av, wB.z, acc[rr][6]);
            acc[rr][7] = fmaf(av, wB.w, acc[rr][7]);
        }
    }
    #pragma unroll
    for (int rr = 0; rr < 4; ++rr) {
        float ov[8];
        #pragma unroll
        for (int c = 0; c < 8; ++c) ov[c] = acc[rr][c] + bo[tx * 8 + c];
        float* outp = out + (size_t)(p0 + ty * 4 + rr) * 128 + tx * 8;
        *(float4*)outp       = *(float4*)ov;
        *(float4*)(outp + 4) = *(float4*)(ov + 4);
    }
}

// ---------------------------------------------------------------------------
extern "C" void kernel_launch(void* const* d_in, const int* in_sizes, int n_in,
                              void* d_out, int out_size, void* d_ws, size_t ws_size,
                              hipStream_t stream) {
    const float* pair = (const float*)d_in[0];
    const float* ln_w = (const float*)d_in[1];
    const float* ln_b = (const float*)d_in[2];
    const float* Wq   = (const float*)d_in[3];
    const float* Wk   = (const float*)d_in[4];
    const float* Wv   = (const float*)d_in[5];
    const float* Wb   = (const float*)d_in[6];
    const float* Wg   = (const float*)d_in[7];
    const float* bg   = (const float*)d_in[8];
    const float* Wo   = (const float*)d_in[9];
    const float* bo   = (const float*)d_in[10];

    // workspace layout (floats): q,k,v,g,go = 65536*128 each; bias_t = 4*65536
    float* ws     = (float*)d_ws;
    float* q      = ws;
    float* k      = ws + (size_t)1 * NPOS * 128;
    float* v      = ws + (size_t)2 * NPOS * 128;
    float* g      = ws + (size_t)3 * NPOS * 128;
    float* go     = ws + (size_t)4 * NPOS * 128;
    float* bias_t = ws + (size_t)5 * NPOS * 128;
    float* out    = (float*)d_out;

    hipLaunchKernelGGL(ln_proj_kernel, dim3(1024), dim3(256), 0, stream,
                       pair, ln_w, ln_b, Wq, Wk, Wv, Wb, Wg, bg, q, k, v, g, bias_t);
    hipLaunchKernelGGL(attn_kernel, dim3(1024), dim3(256), 0, stream,
                       q, k, v, g, bias_t, go);
    hipLaunchKernelGGL(out_proj_kernel, dim3(1024), dim3(256), 0, stream,
                       go, Wo, bo, out);
}

// Round 2
// 470.058 us; speedup vs baseline: 1.1781x; 1.1781x over previous
//
#include <hip/hip_runtime.h>
#include <math.h>

// Sizes (hard-coded per reference): B=1, L=256, D=128, H=4, DH=32
// positions P = L*L = 65536; HD = H*DH = 128
#define NPOS 65536

// ---------------------------------------------------------------------------
// Kernel A: LayerNorm + projections (q,k,v,g) + bias (transposed store)
// grid 1024 x 256 threads; each block handles 64 positions (rows).
// ---------------------------------------------------------------------------
__global__ __launch_bounds__(256) void ln_proj_kernel(
    const float* __restrict__ pair, const float* __restrict__ ln_w, const float* __restrict__ ln_b,
    const float* __restrict__ Wq, const float* __restrict__ Wk, const float* __restrict__ Wv,
    const float* __restrict__ Wb, const float* __restrict__ Wg, const float* __restrict__ bg,
    float* __restrict__ q, float* __restrict__ k, float* __restrict__ v,
    float* __restrict__ g, float* __restrict__ bias_t)
{
    __shared__ float xn[64][140];   // pad 140: 16B-aligned rows, 2-way-max bank aliasing
    __shared__ float wl[64][64];    // K-half x 64-col weight tile
    __shared__ float wbl[512];      // Wb (128x4)

    const int tid = threadIdx.x;
    const int p0  = blockIdx.x * 64;

    // ---- load pair rows into LDS (float4, coalesced) ----
    for (int i = tid; i < 64 * 32; i += 256) {
        int row = i >> 5, c4 = (i & 31) * 4;
        float4 val = *(const float4*)(pair + (size_t)(p0 + row) * 128 + c4);
        xn[row][c4 + 0] = val.x; xn[row][c4 + 1] = val.y;
        xn[row][c4 + 2] = val.z; xn[row][c4 + 3] = val.w;
    }
    wbl[tid]       = Wb[tid];
    wbl[tid + 256] = Wb[tid + 256];
    __syncthreads();

    // ---- LayerNorm: 4 threads per row, interleaved columns c = s + 4*ii ----
    {
        int r = tid >> 2, s = tid & 3;
        float sum = 0.f, sq = 0.f;
        #pragma unroll
        for (int ii = 0; ii < 32; ++ii) {
            float x = xn[r][s + ii * 4];
            sum += x; sq += x * x;
        }
        sum += __shfl_xor(sum, 1); sq += __shfl_xor(sq, 1);
        sum += __shfl_xor(sum, 2); sq += __shfl_xor(sq, 2);
        float mean = sum * (1.f / 128.f);
        float var  = sq * (1.f / 128.f) - mean * mean;
        float rstd = rsqrtf(var + 1e-5f);
        #pragma unroll
        for (int ii = 0; ii < 32; ++ii) {
            int c = s + ii * 4;
            xn[r][c] = (xn[r][c] - mean) * rstd * ln_w[c] + ln_b[c];
        }
    }
    __syncthreads();

    // ---- bias: one (row,h) per thread; store transposed bias_t[h][k][j] ----
    {
        int rr = tid >> 2, h = tid & 3;
        float dot = 0.f;
        #pragma unroll 8
        for (int kk = 0; kk < 128; ++kk) dot += xn[rr][kk] * wbl[kk * 4 + h];
        int p = p0 + rr;
        int a = p >> 8, bb = p & 255;         // p = (j, k) position
        bias_t[h * NPOS + bb * 256 + a] = dot;
    }

    // ---- main GEMM: 8 chunks of 64 cols (q|k|v|g), K split into 2 halves ----
    const int ty = tid >> 4, tx = tid & 15;   // 16x16 threads -> 4x4 microtile
    const float scale = 0.17677669529663687f; // 1/sqrt(32)

    for (int chunk = 0; chunk < 8; ++chunk) {
        int m = chunk >> 1, col0 = (chunk & 1) * 64;
        const float* W; float* dstp;
        if      (m == 0) { W = Wq; dstp = q; }
        else if (m == 1) { W = Wk; dstp = k; }
        else if (m == 2) { W = Wv; dstp = v; }
        else             { W = Wg; dstp = g; }

        float acc[4][4] = {};
        for (int khalf = 0; khalf < 2; ++khalf) {
            __syncthreads();
            for (int i = tid; i < 64 * 16; i += 256) {
                int row = i >> 4, c4 = (i & 15) * 4;
                *(float4*)&wl[row][c4] =
                    *(const float4*)(W + (khalf * 64 + row) * 128 + col0 + c4);
            }
            __syncthreads();
            int kbase = khalf * 64;
            #pragma unroll 4
            for (int kk = 0; kk < 64; kk += 4) {
                float4 w0 = *(const float4*)&wl[kk + 0][tx * 4];
                float4 w1 = *(const float4*)&wl[kk + 1][tx * 4];
                float4 w2 = *(const float4*)&wl[kk + 2][tx * 4];
                float4 w3 = *(const float4*)&wl[kk + 3][tx * 4];
                #pragma unroll
                for (int rr = 0; rr < 4; ++rr) {
                    float4 av = *(const float4*)&xn[ty * 4 + rr][kbase + kk];
                    acc[rr][0] = fmaf(av.x, w0.x, fmaf(av.y, w1.x, fmaf(av.z, w2.x, fmaf(av.w, w3.x, acc[rr][0]))));
                    acc[rr][1] = fmaf(av.x, w0.y, fmaf(av.y, w1.y, fmaf(av.z, w2.y, fmaf(av.w, w3.y, acc[rr][1]))));
                    acc[rr][2] = fmaf(av.x, w0.z, fmaf(av.y, w1.z, fmaf(av.z, w2.z, fmaf(av.w, w3.z, acc[rr][2]))));
                    acc[rr][3] = fmaf(av.x, w0.w, fmaf(av.y, w1.w, fmaf(av.z, w2.w, fmaf(av.w, w3.w, acc[rr][3]))));
                }
            }
        }
        // epilogue: q-scale / g-sigmoid, store float4
        #pragma unroll
        for (int rr = 0; rr < 4; ++rr) {
            float ov[4];
            #pragma unroll
            for (int c = 0; c < 4; ++c) {
                float val = acc[rr][c];
                if (m == 0) val *= scale;
                if (m == 3) {
                    val += bg[col0 + tx * 4 + c];
                    val = 1.f / (1.f + __expf(-val));
                }
                ov[c] = val;
            }
            *(float4*)(dstp + (size_t)(p0 + ty * 4 + rr) * 128 + col0 + tx * 4) = *(float4*)ov;
        }
    }
}

// ---------------------------------------------------------------------------
// Kernel B: triangle attention, one block per (i,h), 256 threads = 4 waves.
// Round-2 restructure (was LDS-broadcast-bound: 371 LDS cyc vs 128 VALU cyc
// per key):
//   * K/V staged [k][d] (rows of 32 floats) -> per key, 16 wave-uniform
//     ds_read_b128 broadcasts (192 cyc) instead of 64 ds_read_b32 (371 cyc).
//   * 2 queries per lane (register tile): 128 FMA = 256 VALU cyc per key ->
//     VALU-bound.
//   * split-K across waves: waves 0,1 handle k in [0,128), waves 2,3 handle
//     k in [128,256); flash partials (m,l,acc) merged through LDS (space
//     reused from K/V after a barrier).
// LDS 64 KB -> 2 blocks/CU; __launch_bounds__(256,2) pins VGPR<=256.
// ---------------------------------------------------------------------------
__global__ __launch_bounds__(256, 2) void attn_kernel(
    const float* __restrict__ q, const float* __restrict__ k, const float* __restrict__ v,
    const float* __restrict__ g, const float* __restrict__ bias_t, float* __restrict__ go)
{
    __shared__ float lds[16384];          // 64 KB
    float* Kl = lds;                      // [256][32]
    float* Vl = lds + 8192;               // [256][32]

    const int tid  = threadIdx.x;
    const int wid  = tid >> 6;
    const int lane = tid & 63;
    const int i = blockIdx.x >> 2, h = blockIdx.x & 3;
    const size_t base = (size_t)i * 256 * 128 + (size_t)h * 32;

    // ---- stage K,V rows: thread t -> row t (one-time; minor bank aliasing ok)
    {
        const float4* kr = (const float4*)(k + base + (size_t)tid * 128);
        const float4* vr = (const float4*)(v + base + (size_t)tid * 128);
        float4* kd = (float4*)(Kl + tid * 32);
        float4* vd = (float4*)(Vl + tid * 32);
        #pragma unroll
        for (int d4 = 0; d4 < 8; ++d4) { kd[d4] = kr[d4]; vd[d4] = vr[d4]; }
    }

    // ---- query mapping: j0 = jbase+lane, j1 = j0+64; k-range per wave pair
    const int jbase  = (wid & 1) * 128;
    const int j0     = jbase + lane;
    const int k0base = (wid >> 1) * 128;

    float q_r[2][32];
    #pragma unroll
    for (int jj = 0; jj < 2; ++jj) {
        const float4* qr = (const float4*)(q + base + (size_t)(j0 + jj * 64) * 128);
        #pragma unroll
        for (int d4 = 0; d4 < 8; ++d4) {
            float4 t = qr[d4];
            q_r[jj][d4 * 4 + 0] = t.x; q_r[jj][d4 * 4 + 1] = t.y;
            q_r[jj][d4 * 4 + 2] = t.z; q_r[jj][d4 * 4 + 3] = t.w;
        }
    }
    __syncthreads();

    const float* bt = bias_t + (size_t)h * NPOS + j0;   // + kpos*256 (+64 for j1)

    float m0 = -1e30f, l0 = 0.f, m1 = -1e30f, l1 = 0.f;
    float acc0[32] = {}, acc1[32] = {};

    for (int kc = 0; kc < 128; kc += 8) {
        const int kk0 = k0base + kc;

        // prefetch bias for the chunk (coalesced across lanes)
        float b_r[2][8];
        #pragma unroll
        for (int t = 0; t < 8; ++t) {
            b_r[0][t] = bt[(size_t)(kk0 + t) * 256];
            b_r[1][t] = bt[(size_t)(kk0 + t) * 256 + 64];
        }

        // scores for chunk (K rows via wave-uniform b128 broadcasts)
        float s0[8], s1[8];
        float cm0 = m0, cm1 = m1;
        #pragma unroll
        for (int t = 0; t < 8; ++t) {
            const float4* krow = (const float4*)(Kl + (kk0 + t) * 32);
            float a0 = b_r[0][t], a1 = b_r[1][t];
            #pragma unroll
            for (int d4 = 0; d4 < 8; ++d4) {
                float4 kv = krow[d4];
                a0 = fmaf(q_r[0][d4 * 4 + 0], kv.x, a0);
                a1 = fmaf(q_r[1][d4 * 4 + 0], kv.x, a1);
                a0 = fmaf(q_r[0][d4 * 4 + 1], kv.y, a0);
                a1 = fmaf(q_r[1][d4 * 4 + 1], kv.y, a1);
                a0 = fmaf(q_r[0][d4 * 4 + 2], kv.z, a0);
                a1 = fmaf(q_r[1][d4 * 4 + 2], kv.z, a1);
                a0 = fmaf(q_r[0][d4 * 4 + 3], kv.w, a0);
                a1 = fmaf(q_r[1][d4 * 4 + 3], kv.w, a1);
            }
            s0[t] = a0; s1[t] = a1;
            cm0 = fmaxf(cm0, a0); cm1 = fmaxf(cm1, a1);
        }

        // online-softmax rescale
        float sc0 = __expf(m0 - cm0), sc1 = __expf(m1 - cm1);
        m0 = cm0; m1 = cm1; l0 *= sc0; l1 *= sc1;
        #pragma unroll
        for (int d = 0; d < 32; ++d) { acc0[d] *= sc0; acc1[d] *= sc1; }

        // P @ V for chunk
        #pragma unroll
        for (int t = 0; t < 8; ++t) {
            float p0 = __expf(s0[t] - m0), p1 = __expf(s1[t] - m1);
            l0 += p0; l1 += p1;
            const float4* vrow = (const float4*)(Vl + (kk0 + t) * 32);
            #pragma unroll
            for (int d4 = 0; d4 < 8; ++d4) {
                float4 vv = vrow[d4];
                acc0[d4 * 4 + 0] = fmaf(p0, vv.x, acc0[d4 * 4 + 0]);
                acc1[d4 * 4 + 0] = fmaf(p1, vv.x, acc1[d4 * 4 + 0]);
                acc0[d4 * 4 + 1] = fmaf(p0, vv.y, acc0[d4 * 4 + 1]);
                acc1[d4 * 4 + 1] = fmaf(p1, vv.y, acc1[d4 * 4 + 1]);
                acc0[d4 * 4 + 2] = fmaf(p0, vv.z, acc0[d4 * 4 + 2]);
                acc1[d4 * 4 + 2] = fmaf(p1, vv.z, acc1[d4 * 4 + 2]);
                acc0[d4 * 4 + 3] = fmaf(p0, vv.w, acc0[d4 * 4 + 3]);
                acc1[d4 * 4 + 3] = fmaf(p1, vv.w, acc1[d4 * 4 + 3]);
            }
        }
    }

    // ---- split-K combine through LDS (reuse K/V space) ----
    __syncthreads();
    float* accbuf = lds;            // [256][36] = 9216 floats (pad 36 vs conflicts)
    float* mbuf   = lds + 9216;     // [256]
    float* lbuf   = lds + 9472;     // [256]

    if (wid >= 2) {                 // high-k waves publish partials
        #pragma unroll
        for (int jj = 0; jj < 2; ++jj) {
            int j = j0 + jj * 64;
            float4* a = (float4*)(accbuf + j * 36);
            #pragma unroll
            for (int d4 = 0; d4 < 8; ++d4) {
                float4 t;
                if (jj == 0) t = make_float4(acc0[d4*4], acc0[d4*4+1], acc0[d4*4+2], acc0[d4*4+3]);
                else         t = make_float4(acc1[d4*4], acc1[d4*4+1], acc1[d4*4+2], acc1[d4*4+3]);
                a[d4] = t;
            }
            mbuf[j] = (jj == 0) ? m0 : m1;
            lbuf[j] = (jj == 0) ? l0 : l1;
        }
    }
    __syncthreads();

    if (wid < 2) {                  // low-k waves merge + gated epilogue
        #pragma unroll
        for (int jj = 0; jj < 2; ++jj) {
            int j = j0 + jj * 64;
            float ml = (jj == 0) ? m0 : m1;
            float ll = (jj == 0) ? l0 : l1;
            float mh = mbuf[j], lh = lbuf[j];
            float mn = fmaxf(ml, mh);
            float al = __expf(ml - mn), ah = __expf(mh - mn);
            float inv = 1.f / (ll * al + lh * ah);

            const float4* ar = (const float4*)(accbuf + j * 36);
            const float4* gr = (const float4*)(g + base + (size_t)j * 128);
            float4*       wo = (float4*)(go + base + (size_t)j * 128);
            #pragma unroll
            for (int d4 = 0; d4 < 8; ++d4) {
                float4 hv = ar[d4];
                float4 gv = gr[d4];
                float o0, o1, o2, o3;
                if (jj == 0) {
                    o0 = (acc0[d4*4+0] * al + hv.x * ah) * inv * gv.x;
                    o1 = (acc0[d4*4+1] * al + hv.y * ah) * inv * gv.y;
                    o2 = (acc0[d4*4+2] * al + hv.z * ah) * inv * gv.z;
                    o3 = (acc0[d4*4+3] * al + hv.w * ah) * inv * gv.w;
                } else {
                    o0 = (acc1[d4*4+0] * al + hv.x * ah) * inv * gv.x;
                    o1 = (acc1[d4*4+1] * al + hv.y * ah) * inv * gv.y;
                    o2 = (acc1[d4*4+2] * al + hv.z * ah) * inv * gv.z;
                    o3 = (acc1[d4*4+3] * al + hv.w * ah) * inv * gv.w;
                }
                wo[d4] = make_float4(o0, o1, o2, o3);
            }
        }
    }
}

// ---------------------------------------------------------------------------
// Kernel C: out = go @ Wo + bo.  64 rows/block; A-tile in LDS, Wo via L1/L2.
// ---------------------------------------------------------------------------
__global__ __launch_bounds__(256) void out_proj_kernel(
    const float* __restrict__ go, const float* __restrict__ Wo, const float* __restrict__ bo,
    float* __restrict__ out)
{
    __shared__ float at[64][140];
    const int tid = threadIdx.x;
    const int p0  = blockIdx.x * 64;

    for (int i = tid; i < 64 * 32; i += 256) {
        int row = i >> 5, c4 = (i & 31) * 4;
        float4 val = *(const float4*)(go + (size_t)(p0 + row) * 128 + c4);
        at[row][c4 + 0] = val.x; at[row][c4 + 1] = val.y;
        at[row][c4 + 2] = val.z; at[row][c4 + 3] = val.w;
    }
    __syncthreads();

    const int ty = tid >> 4, tx = tid & 15;   // 4 rows x 8 cols per thread
    float acc[4][8] = {};
    #pragma unroll 2
    for (int kk = 0; kk < 128; ++kk) {
        float4 wA = *(const float4*)(Wo + kk * 128 + tx * 8);
        float4 wB = *(const float4*)(Wo + kk * 128 + tx * 8 + 4);
        #pragma unroll
        for (int rr = 0; rr < 4; ++rr) {
            float av = at[ty * 4 + rr][kk];
            acc[rr][0] = fmaf(av, wA.x, acc[rr][0]);
            acc[rr][1] = fmaf(av, wA.y, acc[rr][1]);
            acc[rr][2] = fmaf(av, wA.z, acc[rr][2]);
            acc[rr][3] = fmaf(av, wA.w, acc[rr][3]);
            acc[rr][4] = fmaf(av, wB.x, acc[rr][4]);
            acc[rr][5] = fmaf(av, wB.y, acc[rr][5]);
            acc[rr][6] = fmaf(av, wB.z, acc[rr][6]);
            acc[rr][7] = fmaf(av, wB.w, acc[rr][7]);
        }
    }
    #pragma unroll
    for (int rr = 0; rr < 4; ++rr) {
        float ov[8];
        #pragma unroll
        for (int c = 0; c < 8; ++c) ov[c] = acc[rr][c] + bo[tx * 8 + c];
        float* outp = out + (size_t)(p0 + ty * 4 + rr) * 128 + tx * 8;
        *(float4*)outp       = *(float4*)ov;
        *(float4*)(outp + 4) = *(float4*)(ov + 4);
    }
}

// ---------------------------------------------------------------------------
extern "C" void kernel_launch(void* const* d_in, const int* in_sizes, int n_in,
                              void* d_out, int out_size, void* d_ws, size_t ws_size,
                              hipStream_t stream) {
    const float* pair = (const float*)d_in[0];
    const float* ln_w = (const float*)d_in[1];
    const float* ln_b = (const float*)d_in[2];
    const float* Wq   = (const float*)d_in[3];
    const float* Wk   = (const float*)d_in[4];
    const float* Wv   = (const float*)d_in[5];
    const float* Wb   = (const float*)d_in[6];
    const float* Wg   = (const float*)d_in[7];
    const float* bg   = (const float*)d_in[8];
    const float* Wo   = (const float*)d_in[9];
    const float* bo   = (const float*)d_in[10];

    // workspace layout (floats): q,k,v,g,go = 65536*128 each; bias_t = 4*65536
    float* ws     = (float*)d_ws;
    float* q      = ws;
    float* k      = ws + (size_t)1 * NPOS * 128;
    float* v      = ws + (size_t)2 * NPOS * 128;
    float* g      = ws + (size_t)3 * NPOS * 128;
    float* go     = ws + (size_t)4 * NPOS * 128;
    float* bias_t = ws + (size_t)5 * NPOS * 128;
    float* out    = (float*)d_out;

    hipLaunchKernelGGL(ln_proj_kernel, dim3(1024), dim3(256), 0, stream,
                       pair, ln_w, ln_b, Wq, Wk, Wv, Wb, Wg, bg, q, k, v, g, bias_t);
    hipLaunchKernelGGL(attn_kernel, dim3(1024), dim3(256), 0, stream,
                       q, k, v, g, bias_t, go);
    hipLaunchKernelGGL(out_proj_kernel, dim3(1024), dim3(256), 0, stream,
                       go, Wo, bo, out);
}

// Round 3
// 444.527 us; speedup vs baseline: 1.2458x; 1.0574x over previous
//
#include <hip/hip_runtime.h>
#include <math.h>

// Sizes (hard-coded per reference): B=1, L=256, D=128, H=4, DH=32
// positions P = L*L = 65536; HD = H*DH = 128
#define NPOS 65536

typedef _Float16 f16x8 __attribute__((ext_vector_type(8)));
typedef float    f32x4 __attribute__((ext_vector_type(4)));

// ---------------------------------------------------------------------------
// Kernel P: split W{q,k,v,g} (fp32, [k=128][n=128] each) into transposed f16
// hi/lo planes: Wt[n_global=512][k=128], n_global = mat*128+n.
// lo is pre-scaled by 2^11 to stay in f16 normal range.
// ---------------------------------------------------------------------------
__global__ __launch_bounds__(256) void split_w_kernel(
    const float* __restrict__ Wq, const float* __restrict__ Wk,
    const float* __restrict__ Wv, const float* __restrict__ Wg,
    _Float16* __restrict__ Wt_hi, _Float16* __restrict__ Wt_lo)
{
    int t = blockIdx.x * 256 + threadIdx.x;       // 0..65535
    int ng = t >> 7, kk = t & 127;
    int mat = ng >> 7, n = ng & 127;
    const float* W = (mat == 0) ? Wq : (mat == 1) ? Wk : (mat == 2) ? Wv : Wg;
    float x = W[kk * 128 + n];
    _Float16 h = (_Float16)x;
    _Float16 lo = (_Float16)((x - (float)h) * 2048.0f);
    Wt_hi[t] = h;
    Wt_lo[t] = lo;
}

// ---------------------------------------------------------------------------
// Kernel A (round-3 rewrite): LayerNorm in registers + split-f16 MFMA GEMM.
// Was LDS-pipe-bound (0.5 float/FMA -> 98k LDS cyc/block = 164us floor).
// Now: x hi/lo f16 in LDS; each wave holds its A-fragments (16 rows x K=128)
// in registers (8 LDS reads total); B streamed from pre-split Wt via
// global 16B loads (L1/L2-resident). 3 MFMAs per tile (hi*hi + scaled cross).
// Bias (H=4) via fp32 VALU from LN registers. LDS 34.8KB -> 4 blocks/CU.
// ---------------------------------------------------------------------------
__global__ __launch_bounds__(256, 4) void ln_proj_kernel(
    const float* __restrict__ pair, const float* __restrict__ ln_w, const float* __restrict__ ln_b,
    const float* __restrict__ Wb, const float* __restrict__ bg,
    const _Float16* __restrict__ Wt_hi, const _Float16* __restrict__ Wt_lo,
    float* __restrict__ q, float* __restrict__ k, float* __restrict__ v,
    float* __restrict__ g, float* __restrict__ bias_t)
{
    __shared__ _Float16 xh[64][136];   // pad 136: 16B rows, 2-way-max on frag reads
    __shared__ _Float16 xl[64][136];

    const int tid = threadIdx.x;
    const int p0  = blockIdx.x * 64;
    const int r   = tid >> 2;          // row 0..63
    const int cb  = (tid & 3) * 32;    // col base (4 threads/row)

    // ---- load 32 pair values (float4, coalesced) ----
    float xv[32];
    {
        const float4* pr = (const float4*)(pair + (size_t)(p0 + r) * 128 + cb);
        #pragma unroll
        for (int i = 0; i < 8; ++i) {
            float4 t = pr[i];
            xv[i * 4 + 0] = t.x; xv[i * 4 + 1] = t.y;
            xv[i * 4 + 2] = t.z; xv[i * 4 + 3] = t.w;
        }
    }
    // ---- LN stats across the 4 threads of the row ----
    float sum = 0.f, sq = 0.f;
    #pragma unroll
    for (int i = 0; i < 32; ++i) { sum += xv[i]; sq += xv[i] * xv[i]; }
    sum += __shfl_xor(sum, 1); sq += __shfl_xor(sq, 1);
    sum += __shfl_xor(sum, 2); sq += __shfl_xor(sq, 2);
    float mean = sum * (1.f / 128.f);
    float var  = sq * (1.f / 128.f) - mean * mean;
    float rstd = rsqrtf(var + 1e-5f);

    // ---- normalize, split to f16 hi/lo, store to LDS; bias partial dots ----
    float b0 = 0.f, b1 = 0.f, b2 = 0.f, b3 = 0.f;
    #pragma unroll
    for (int i8 = 0; i8 < 4; ++i8) {
        float4 lw0 = *(const float4*)(ln_w + cb + i8 * 8);
        float4 lw1 = *(const float4*)(ln_w + cb + i8 * 8 + 4);
        float4 lb0 = *(const float4*)(ln_b + cb + i8 * 8);
        float4 lb1 = *(const float4*)(ln_b + cb + i8 * 8 + 4);
        float lw[8] = {lw0.x, lw0.y, lw0.z, lw0.w, lw1.x, lw1.y, lw1.z, lw1.w};
        float lb[8] = {lb0.x, lb0.y, lb0.z, lb0.w, lb1.x, lb1.y, lb1.z, lb1.w};
        f16x8 hv, lv;
        #pragma unroll
        for (int j = 0; j < 8; ++j) {
            int i = i8 * 8 + j;
            float xn = (xv[i] - mean) * rstd * lw[j] + lb[j];
            _Float16 h = (_Float16)xn;
            hv[j] = h;
            lv[j] = (_Float16)((xn - (float)h) * 2048.0f);
            float4 wb = *(const float4*)(Wb + (size_t)(cb + i) * 4);
            b0 = fmaf(xn, wb.x, b0); b1 = fmaf(xn, wb.y, b1);
            b2 = fmaf(xn, wb.z, b2); b3 = fmaf(xn, wb.w, b3);
        }
        *(f16x8*)&xh[r][cb + i8 * 8] = hv;
        *(f16x8*)&xl[r][cb + i8 * 8] = lv;
    }
    // reduce bias dots across the 4 threads of the row, store transposed
    b0 += __shfl_xor(b0, 1); b1 += __shfl_xor(b1, 1);
    b2 += __shfl_xor(b2, 1); b3 += __shfl_xor(b3, 1);
    b0 += __shfl_xor(b0, 2); b1 += __shfl_xor(b1, 2);
    b2 += __shfl_xor(b2, 2); b3 += __shfl_xor(b3, 2);
    if ((tid & 3) == 0) {
        int p = p0 + r;
        int a = p >> 8, bb = p & 255;          // bias_t[h][k][j]
        bias_t[0 * NPOS + bb * 256 + a] = b0;
        bias_t[1 * NPOS + bb * 256 + a] = b1;
        bias_t[2 * NPOS + bb * 256 + a] = b2;
        bias_t[3 * NPOS + bb * 256 + a] = b3;
    }
    __syncthreads();

    // ---- MFMA phase: wave w -> row-tile w (16 rows). A frags in registers. ----
    const int w  = tid >> 6, l = tid & 63;
    const int lm = l & 15, lg = l >> 4;
    const int arow = w * 16 + lm;

    f16x8 ah[4], al[4];
    #pragma unroll
    for (int kt = 0; kt < 4; ++kt) {
        ah[kt] = *(const f16x8*)&xh[arow][kt * 32 + lg * 8];
        al[kt] = *(const f16x8*)&xl[arow][kt * 32 + lg * 8];
    }

    const float scale = 0.17677669529663687f;  // 1/sqrt(32)
    for (int ct2 = 0; ct2 < 16; ++ct2) {
        const int ct0 = ct2 * 2, ct1 = ct0 + 1;
        f32x4 ah0 = {0.f, 0.f, 0.f, 0.f}, ac0 = {0.f, 0.f, 0.f, 0.f};
        f32x4 ah1 = {0.f, 0.f, 0.f, 0.f}, ac1 = {0.f, 0.f, 0.f, 0.f};
        #pragma unroll
        for (int kt = 0; kt < 4; ++kt) {
            const size_t koff = (size_t)(kt * 32 + lg * 8);
            f16x8 bh0 = *(const f16x8*)(Wt_hi + (size_t)(ct0 * 16 + lm) * 128 + koff);
            f16x8 bl0 = *(const f16x8*)(Wt_lo + (size_t)(ct0 * 16 + lm) * 128 + koff);
            f16x8 bh1 = *(const f16x8*)(Wt_hi + (size_t)(ct1 * 16 + lm) * 128 + koff);
            f16x8 bl1 = *(const f16x8*)(Wt_lo + (size_t)(ct1 * 16 + lm) * 128 + koff);
            ah0 = __builtin_amdgcn_mfma_f32_16x16x32_f16(ah[kt], bh0, ah0, 0, 0, 0);
            ac0 = __builtin_amdgcn_mfma_f32_16x16x32_f16(al[kt], bh0, ac0, 0, 0, 0);
            ac0 = __builtin_amdgcn_mfma_f32_16x16x32_f16(ah[kt], bl0, ac0, 0, 0, 0);
            ah1 = __builtin_amdgcn_mfma_f32_16x16x32_f16(ah[kt], bh1, ah1, 0, 0, 0);
            ac1 = __builtin_amdgcn_mfma_f32_16x16x32_f16(al[kt], bh1, ac1, 0, 0, 0);
            ac1 = __builtin_amdgcn_mfma_f32_16x16x32_f16(ah[kt], bl1, ac1, 0, 0, 0);
        }
        #pragma unroll
        for (int half = 0; half < 2; ++half) {
            const int ct  = half ? ct1 : ct0;
            const f32x4 hh = half ? ah1 : ah0;
            const f32x4 cc = half ? ac1 : ac0;
            const int mat = ct >> 3, c0 = (ct & 7) * 16;
            float* dst = (mat == 0) ? q : (mat == 1) ? k : (mat == 2) ? v : g;
            const int col = c0 + lm;
            float bgv = (mat == 3) ? bg[col] : 0.f;
            #pragma unroll
            for (int rr = 0; rr < 4; ++rr) {
                float val = hh[rr] + cc[rr] * (1.0f / 2048.0f);
                if (mat == 0) val *= scale;
                if (mat == 3) val = 1.f / (1.f + __expf(-(val + bgv)));
                int row = p0 + w * 16 + lg * 4 + rr;
                dst[(size_t)row * 128 + col] = val;
            }
        }
    }
}

// ---------------------------------------------------------------------------
// Kernel B: triangle attention, one block per (i,h), 256 threads = 4 waves.
// (unchanged this round; known LDS-broadcast-bound ~180us -> MFMA next round)
// ---------------------------------------------------------------------------
__global__ __launch_bounds__(256, 2) void attn_kernel(
    const float* __restrict__ q, const float* __restrict__ k, const float* __restrict__ v,
    const float* __restrict__ g, const float* __restrict__ bias_t, float* __restrict__ go)
{
    __shared__ float lds[16384];          // 64 KB
    float* Kl = lds;                      // [256][32]
    float* Vl = lds + 8192;               // [256][32]

    const int tid  = threadIdx.x;
    const int wid  = tid >> 6;
    const int lane = tid & 63;
    const int i = blockIdx.x >> 2, h = blockIdx.x & 3;
    const size_t base = (size_t)i * 256 * 128 + (size_t)h * 32;

    {
        const float4* kr = (const float4*)(k + base + (size_t)tid * 128);
        const float4* vr = (const float4*)(v + base + (size_t)tid * 128);
        float4* kd = (float4*)(Kl + tid * 32);
        float4* vd = (float4*)(Vl + tid * 32);
        #pragma unroll
        for (int d4 = 0; d4 < 8; ++d4) { kd[d4] = kr[d4]; vd[d4] = vr[d4]; }
    }

    const int jbase  = (wid & 1) * 128;
    const int j0     = jbase + lane;
    const int k0base = (wid >> 1) * 128;

    float q_r[2][32];
    #pragma unroll
    for (int jj = 0; jj < 2; ++jj) {
        const float4* qr = (const float4*)(q + base + (size_t)(j0 + jj * 64) * 128);
        #pragma unroll
        for (int d4 = 0; d4 < 8; ++d4) {
            float4 t = qr[d4];
            q_r[jj][d4 * 4 + 0] = t.x; q_r[jj][d4 * 4 + 1] = t.y;
            q_r[jj][d4 * 4 + 2] = t.z; q_r[jj][d4 * 4 + 3] = t.w;
        }
    }
    __syncthreads();

    const float* bt = bias_t + (size_t)h * NPOS + j0;

    float m0 = -1e30f, l0 = 0.f, m1 = -1e30f, l1 = 0.f;
    float acc0[32] = {}, acc1[32] = {};

    for (int kc = 0; kc < 128; kc += 8) {
        const int kk0 = k0base + kc;

        float b_r[2][8];
        #pragma unroll
        for (int t = 0; t < 8; ++t) {
            b_r[0][t] = bt[(size_t)(kk0 + t) * 256];
            b_r[1][t] = bt[(size_t)(kk0 + t) * 256 + 64];
        }

        float s0[8], s1[8];
        float cm0 = m0, cm1 = m1;
        #pragma unroll
        for (int t = 0; t < 8; ++t) {
            const float4* krow = (const float4*)(Kl + (kk0 + t) * 32);
            float a0 = b_r[0][t], a1 = b_r[1][t];
            #pragma unroll
            for (int d4 = 0; d4 < 8; ++d4) {
                float4 kv = krow[d4];
                a0 = fmaf(q_r[0][d4 * 4 + 0], kv.x, a0);
                a1 = fmaf(q_r[1][d4 * 4 + 0], kv.x, a1);
                a0 = fmaf(q_r[0][d4 * 4 + 1], kv.y, a0);
                a1 = fmaf(q_r[1][d4 * 4 + 1], kv.y, a1);
                a0 = fmaf(q_r[0][d4 * 4 + 2], kv.z, a0);
                a1 = fmaf(q_r[1][d4 * 4 + 2], kv.z, a1);
                a0 = fmaf(q_r[0][d4 * 4 + 3], kv.w, a0);
                a1 = fmaf(q_r[1][d4 * 4 + 3], kv.w, a1);
            }
            s0[t] = a0; s1[t] = a1;
            cm0 = fmaxf(cm0, a0); cm1 = fmaxf(cm1, a1);
        }

        float sc0 = __expf(m0 - cm0), sc1 = __expf(m1 - cm1);
        m0 = cm0; m1 = cm1; l0 *= sc0; l1 *= sc1;
        #pragma unroll
        for (int d = 0; d < 32; ++d) { acc0[d] *= sc0; acc1[d] *= sc1; }

        #pragma unroll
        for (int t = 0; t < 8; ++t) {
            float p0v = __expf(s0[t] - m0), p1v = __expf(s1[t] - m1);
            l0 += p0v; l1 += p1v;
            const float4* vrow = (const float4*)(Vl + (kk0 + t) * 32);
            #pragma unroll
            for (int d4 = 0; d4 < 8; ++d4) {
                float4 vv = vrow[d4];
                acc0[d4 * 4 + 0] = fmaf(p0v, vv.x, acc0[d4 * 4 + 0]);
                acc1[d4 * 4 + 0] = fmaf(p1v, vv.x, acc1[d4 * 4 + 0]);
                acc0[d4 * 4 + 1] = fmaf(p0v, vv.y, acc0[d4 * 4 + 1]);
                acc1[d4 * 4 + 1] = fmaf(p1v, vv.y, acc1[d4 * 4 + 1]);
                acc0[d4 * 4 + 2] = fmaf(p0v, vv.z, acc0[d4 * 4 + 2]);
                acc1[d4 * 4 + 2] = fmaf(p1v, vv.z, acc1[d4 * 4 + 2]);
                acc0[d4 * 4 + 3] = fmaf(p0v, vv.w, acc0[d4 * 4 + 3]);
                acc1[d4 * 4 + 3] = fmaf(p1v, vv.w, acc1[d4 * 4 + 3]);
            }
        }
    }

    __syncthreads();
    float* accbuf = lds;            // [256][36]
    float* mbuf   = lds + 9216;
    float* lbuf   = lds + 9472;

    if (wid >= 2) {
        #pragma unroll
        for (int jj = 0; jj < 2; ++jj) {
            int j = j0 + jj * 64;
            float4* a = (float4*)(accbuf + j * 36);
            #pragma unroll
            for (int d4 = 0; d4 < 8; ++d4) {
                float4 t;
                if (jj == 0) t = make_float4(acc0[d4*4], acc0[d4*4+1], acc0[d4*4+2], acc0[d4*4+3]);
                else         t = make_float4(acc1[d4*4], acc1[d4*4+1], acc1[d4*4+2], acc1[d4*4+3]);
                a[d4] = t;
            }
            mbuf[j] = (jj == 0) ? m0 : m1;
            lbuf[j] = (jj == 0) ? l0 : l1;
        }
    }
    __syncthreads();

    if (wid < 2) {
        #pragma unroll
        for (int jj = 0; jj < 2; ++jj) {
            int j = j0 + jj * 64;
            float ml = (jj == 0) ? m0 : m1;
            float ll = (jj == 0) ? l0 : l1;
            float mh = mbuf[j], lh = lbuf[j];
            float mn = fmaxf(ml, mh);
            float alw = __expf(ml - mn), ahw = __expf(mh - mn);
            float inv = 1.f / (ll * alw + lh * ahw);

            const float4* ar = (const float4*)(accbuf + j * 36);
            const float4* gr = (const float4*)(g + base + (size_t)j * 128);
            float4*       wo = (float4*)(go + base + (size_t)j * 128);
            #pragma unroll
            for (int d4 = 0; d4 < 8; ++d4) {
                float4 hv = ar[d4];
                float4 gv = gr[d4];
                float o0, o1, o2, o3;
                if (jj == 0) {
                    o0 = (acc0[d4*4+0] * alw + hv.x * ahw) * inv * gv.x;
                    o1 = (acc0[d4*4+1] * alw + hv.y * ahw) * inv * gv.y;
                    o2 = (acc0[d4*4+2] * alw + hv.z * ahw) * inv * gv.z;
                    o3 = (acc0[d4*4+3] * alw + hv.w * ahw) * inv * gv.w;
                } else {
                    o0 = (acc1[d4*4+0] * alw + hv.x * ahw) * inv * gv.x;
                    o1 = (acc1[d4*4+1] * alw + hv.y * ahw) * inv * gv.y;
                    o2 = (acc1[d4*4+2] * alw + hv.z * ahw) * inv * gv.z;
                    o3 = (acc1[d4*4+3] * alw + hv.w * ahw) * inv * gv.w;
                }
                wo[d4] = make_float4(o0, o1, o2, o3);
            }
        }
    }
}

// ---------------------------------------------------------------------------
// Kernel C: out = go @ Wo + bo.  (unchanged; ~20us, not the bottleneck)
// ---------------------------------------------------------------------------
__global__ __launch_bounds__(256) void out_proj_kernel(
    const float* __restrict__ go, const float* __restrict__ Wo, const float* __restrict__ bo,
    float* __restrict__ out)
{
    __shared__ float at[64][140];
    const int tid = threadIdx.x;
    const int p0  = blockIdx.x * 64;

    for (int i = tid; i < 64 * 32; i += 256) {
        int row = i >> 5, c4 = (i & 31) * 4;
        float4 val = *(const float4*)(go + (size_t)(p0 + row) * 128 + c4);
        at[row][c4 + 0] = val.x; at[row][c4 + 1] = val.y;
        at[row][c4 + 2] = val.z; at[row][c4 + 3] = val.w;
    }
    __syncthreads();

    const int ty = tid >> 4, tx = tid & 15;
    float acc[4][8] = {};
    #pragma unroll 2
    for (int kk = 0; kk < 128; ++kk) {
        float4 wA = *(const float4*)(Wo + kk * 128 + tx * 8);
        float4 wB = *(const float4*)(Wo + kk * 128 + tx * 8 + 4);
        #pragma unroll
        for (int rr = 0; rr < 4; ++rr) {
            float av = at[ty * 4 + rr][kk];
            acc[rr][0] = fmaf(av, wA.x, acc[rr][0]);
            acc[rr][1] = fmaf(av, wA.y, acc[rr][1]);
            acc[rr][2] = fmaf(av, wA.z, acc[rr][2]);
            acc[rr][3] = fmaf(av, wA.w, acc[rr][3]);
            acc[rr][4] = fmaf(av, wB.x, acc[rr][4]);
            acc[rr][5] = fmaf(av, wB.y, acc[rr][5]);
            acc[rr][6] = fmaf(av, wB.z, acc[rr][6]);
            acc[rr][7] = fmaf(av, wB.w, acc[rr][7]);
        }
    }
    #pragma unroll
    for (int rr = 0; rr < 4; ++rr) {
        float ov[8];
        #pragma unroll
        for (int c = 0; c < 8; ++c) ov[c] = acc[rr][c] + bo[tx * 8 + c];
        float* outp = out + (size_t)(p0 + ty * 4 + rr) * 128 + tx * 8;
        *(float4*)outp       = *(float4*)ov;
        *(float4*)(outp + 4) = *(float4*)(ov + 4);
    }
}

// ---------------------------------------------------------------------------
extern "C" void kernel_launch(void* const* d_in, const int* in_sizes, int n_in,
                              void* d_out, int out_size, void* d_ws, size_t ws_size,
                              hipStream_t stream) {
    const float* pair = (const float*)d_in[0];
    const float* ln_w = (const float*)d_in[1];
    const float* ln_b = (const float*)d_in[2];
    const float* Wq   = (const float*)d_in[3];
    const float* Wk   = (const float*)d_in[4];
    const float* Wv   = (const float*)d_in[5];
    const float* Wb   = (const float*)d_in[6];
    const float* Wg   = (const float*)d_in[7];
    const float* bg   = (const float*)d_in[8];
    const float* Wo   = (const float*)d_in[9];
    const float* bo   = (const float*)d_in[10];

    // workspace layout (floats): q,k,v,g,go = 65536*128 each; bias_t = 4*65536
    float* ws     = (float*)d_ws;
    float* q      = ws;
    float* k      = ws + (size_t)1 * NPOS * 128;
    float* v      = ws + (size_t)2 * NPOS * 128;
    float* g      = ws + (size_t)3 * NPOS * 128;
    float* go     = ws + (size_t)4 * NPOS * 128;
    float* bias_t = ws + (size_t)5 * NPOS * 128;
    float* out    = (float*)d_out;

    // Transient scratch for pre-split weights: live only during ln_proj,
    // placed in d_out (out_proj overwrites all of d_out at the end).
    _Float16* Wt_hi = (_Float16*)d_out;
    _Float16* Wt_lo = Wt_hi + (size_t)512 * 128;

    hipLaunchKernelGGL(split_w_kernel, dim3(256), dim3(256), 0, stream,
                       Wq, Wk, Wv, Wg, Wt_hi, Wt_lo);
    hipLaunchKernelGGL(ln_proj_kernel, dim3(1024), dim3(256), 0, stream,
                       pair, ln_w, ln_b, Wb, bg, Wt_hi, Wt_lo, q, k, v, g, bias_t);
    hipLaunchKernelGGL(attn_kernel, dim3(1024), dim3(256), 0, stream,
                       q, k, v, g, bias_t, go);
    hipLaunchKernelGGL(out_proj_kernel, dim3(1024), dim3(256), 0, stream,
                       go, Wo, bo, out);
}

// Round 4
// 365.650 us; speedup vs baseline: 1.5145x; 1.2157x over previous
//
#include <hip/hip_runtime.h>
#include <math.h>

// Sizes (hard-coded per reference): B=1, L=256, D=128, H=4, DH=32
// positions P = L*L = 65536; HD = H*DH = 128
#define NPOS 65536

typedef _Float16 f16x8 __attribute__((ext_vector_type(8)));
typedef _Float16 f16x4 __attribute__((ext_vector_type(4)));
typedef float    f32x4 __attribute__((ext_vector_type(4)));

// ---------------------------------------------------------------------------
// Kernel P: split W{q,k,v,g} (fp32, [k=128][n=128] each) into transposed f16
// hi/lo planes: Wt[n_global=512][k=128], n_global = mat*128+n.
// lo is pre-scaled by 2^11 to stay in f16 normal range.
// ---------------------------------------------------------------------------
__global__ __launch_bounds__(256) void split_w_kernel(
    const float* __restrict__ Wq, const float* __restrict__ Wk,
    const float* __restrict__ Wv, const float* __restrict__ Wg,
    _Float16* __restrict__ Wt_hi, _Float16* __restrict__ Wt_lo)
{
    int t = blockIdx.x * 256 + threadIdx.x;       // 0..65535
    int ng = t >> 7, kk = t & 127;
    int mat = ng >> 7, n = ng & 127;
    const float* W = (mat == 0) ? Wq : (mat == 1) ? Wk : (mat == 2) ? Wv : Wg;
    float x = W[kk * 128 + n];
    _Float16 h = (_Float16)x;
    _Float16 lo = (_Float16)((x - (float)h) * 2048.0f);
    Wt_hi[t] = h;
    Wt_lo[t] = lo;
}

// ---------------------------------------------------------------------------
// Kernel A: LayerNorm in registers + split-f16 MFMA GEMM.
// (unchanged this round except: bias now stored in NATURAL layout
//  bias_n[h][p] = [h][j][k] for the MFMA attention kernel's C-operand init)
// ---------------------------------------------------------------------------
__global__ __launch_bounds__(256, 4) void ln_proj_kernel(
    const float* __restrict__ pair, const float* __restrict__ ln_w, const float* __restrict__ ln_b,
    const float* __restrict__ Wb, const float* __restrict__ bg,
    const _Float16* __restrict__ Wt_hi, const _Float16* __restrict__ Wt_lo,
    float* __restrict__ q, float* __restrict__ k, float* __restrict__ v,
    float* __restrict__ g, float* __restrict__ bias_n)
{
    __shared__ _Float16 xh[64][136];   // pad 136: 16B rows, 2-way-max on frag reads
    __shared__ _Float16 xl[64][136];

    const int tid = threadIdx.x;
    const int p0  = blockIdx.x * 64;
    const int r   = tid >> 2;          // row 0..63
    const int cb  = (tid & 3) * 32;    // col base (4 threads/row)

    // ---- load 32 pair values (float4, coalesced) ----
    float xv[32];
    {
        const float4* pr = (const float4*)(pair + (size_t)(p0 + r) * 128 + cb);
        #pragma unroll
        for (int i = 0; i < 8; ++i) {
            float4 t = pr[i];
            xv[i * 4 + 0] = t.x; xv[i * 4 + 1] = t.y;
            xv[i * 4 + 2] = t.z; xv[i * 4 + 3] = t.w;
        }
    }
    // ---- LN stats across the 4 threads of the row ----
    float sum = 0.f, sq = 0.f;
    #pragma unroll
    for (int i = 0; i < 32; ++i) { sum += xv[i]; sq += xv[i] * xv[i]; }
    sum += __shfl_xor(sum, 1); sq += __shfl_xor(sq, 1);
    sum += __shfl_xor(sum, 2); sq += __shfl_xor(sq, 2);
    float mean = sum * (1.f / 128.f);
    float var  = sq * (1.f / 128.f) - mean * mean;
    float rstd = rsqrtf(var + 1e-5f);

    // ---- normalize, split to f16 hi/lo, store to LDS; bias partial dots ----
    float b0 = 0.f, b1 = 0.f, b2 = 0.f, b3 = 0.f;
    #pragma unroll
    for (int i8 = 0; i8 < 4; ++i8) {
        float4 lw0 = *(const float4*)(ln_w + cb + i8 * 8);
        float4 lw1 = *(const float4*)(ln_w + cb + i8 * 8 + 4);
        float4 lb0 = *(const float4*)(ln_b + cb + i8 * 8);
        float4 lb1 = *(const float4*)(ln_b + cb + i8 * 8 + 4);
        float lw[8] = {lw0.x, lw0.y, lw0.z, lw0.w, lw1.x, lw1.y, lw1.z, lw1.w};
        float lb[8] = {lb0.x, lb0.y, lb0.z, lb0.w, lb1.x, lb1.y, lb1.z, lb1.w};
        f16x8 hv, lv;
        #pragma unroll
        for (int j = 0; j < 8; ++j) {
            int i = i8 * 8 + j;
            float xn = (xv[i] - mean) * rstd * lw[j] + lb[j];
            _Float16 h = (_Float16)xn;
            hv[j] = h;
            lv[j] = (_Float16)((xn - (float)h) * 2048.0f);
            float4 wb = *(const float4*)(Wb + (size_t)(cb + i) * 4);
            b0 = fmaf(xn, wb.x, b0); b1 = fmaf(xn, wb.y, b1);
            b2 = fmaf(xn, wb.z, b2); b3 = fmaf(xn, wb.w, b3);
        }
        *(f16x8*)&xh[r][cb + i8 * 8] = hv;
        *(f16x8*)&xl[r][cb + i8 * 8] = lv;
    }
    // reduce bias dots across the 4 threads of the row, store NATURAL layout
    b0 += __shfl_xor(b0, 1); b1 += __shfl_xor(b1, 1);
    b2 += __shfl_xor(b2, 1); b3 += __shfl_xor(b3, 1);
    b0 += __shfl_xor(b0, 2); b1 += __shfl_xor(b1, 2);
    b2 += __shfl_xor(b2, 2); b3 += __shfl_xor(b3, 2);
    if ((tid & 3) == 0) {
        int p = p0 + r;                        // p = j*256 + kpos
        bias_n[0 * NPOS + p] = b0;
        bias_n[1 * NPOS + p] = b1;
        bias_n[2 * NPOS + p] = b2;
        bias_n[3 * NPOS + p] = b3;
    }
    __syncthreads();

    // ---- MFMA phase: wave w -> row-tile w (16 rows). A frags in registers. ----
    const int w  = tid >> 6, l = tid & 63;
    const int lm = l & 15, lg = l >> 4;
    const int arow = w * 16 + lm;

    f16x8 ah[4], al[4];
    #pragma unroll
    for (int kt = 0; kt < 4; ++kt) {
        ah[kt] = *(const f16x8*)&xh[arow][kt * 32 + lg * 8];
        al[kt] = *(const f16x8*)&xl[arow][kt * 32 + lg * 8];
    }

    const float scale = 0.17677669529663687f;  // 1/sqrt(32)
    for (int ct2 = 0; ct2 < 16; ++ct2) {
        const int ct0 = ct2 * 2, ct1 = ct0 + 1;
        f32x4 ah0 = {0.f, 0.f, 0.f, 0.f}, ac0 = {0.f, 0.f, 0.f, 0.f};
        f32x4 ah1 = {0.f, 0.f, 0.f, 0.f}, ac1 = {0.f, 0.f, 0.f, 0.f};
        #pragma unroll
        for (int kt = 0; kt < 4; ++kt) {
            const size_t koff = (size_t)(kt * 32 + lg * 8);
            f16x8 bh0 = *(const f16x8*)(Wt_hi + (size_t)(ct0 * 16 + lm) * 128 + koff);
            f16x8 bl0 = *(const f16x8*)(Wt_lo + (size_t)(ct0 * 16 + lm) * 128 + koff);
            f16x8 bh1 = *(const f16x8*)(Wt_hi + (size_t)(ct1 * 16 + lm) * 128 + koff);
            f16x8 bl1 = *(const f16x8*)(Wt_lo + (size_t)(ct1 * 16 + lm) * 128 + koff);
            ah0 = __builtin_amdgcn_mfma_f32_16x16x32_f16(ah[kt], bh0, ah0, 0, 0, 0);
            ac0 = __builtin_amdgcn_mfma_f32_16x16x32_f16(al[kt], bh0, ac0, 0, 0, 0);
            ac0 = __builtin_amdgcn_mfma_f32_16x16x32_f16(ah[kt], bl0, ac0, 0, 0, 0);
            ah1 = __builtin_amdgcn_mfma_f32_16x16x32_f16(ah[kt], bh1, ah1, 0, 0, 0);
            ac1 = __builtin_amdgcn_mfma_f32_16x16x32_f16(al[kt], bh1, ac1, 0, 0, 0);
            ac1 = __builtin_amdgcn_mfma_f32_16x16x32_f16(ah[kt], bl1, ac1, 0, 0, 0);
        }
        #pragma unroll
        for (int half = 0; half < 2; ++half) {
            const int ct  = half ? ct1 : ct0;
            const f32x4 hh = half ? ah1 : ah0;
            const f32x4 cc = half ? ac1 : ac0;
            const int mat = ct >> 3, c0 = (ct & 7) * 16;
            float* dst = (mat == 0) ? q : (mat == 1) ? k : (mat == 2) ? v : g;
            const int col = c0 + lm;
            float bgv = (mat == 3) ? bg[col] : 0.f;
            #pragma unroll
            for (int rr = 0; rr < 4; ++rr) {
                float val = hh[rr] + cc[rr] * (1.0f / 2048.0f);
                if (mat == 0) val *= scale;
                if (mat == 3) val = 1.f / (1.f + __expf(-(val + bgv)));
                int row = p0 + w * 16 + lg * 4 + rr;
                dst[(size_t)row * 128 + col] = val;
            }
        }
    }
}

// ---------------------------------------------------------------------------
// Kernel B (round-4 rewrite): MFMA flash attention. One block per (i,h),
// 4 waves x 64 j-rows, chunks of 32 kpos.
//  * S = QK^T: split-f16 (3 MFMA/tile); bias preloaded into MFMA C operand.
//  * online softmax in C-layout regs (rows owned by (lg,rr); butterflies
//    over lm lanes only).
//  * P: f32 LDS round-trip (C-layout -> A-layout), cvt to f16 A-frags.
//  * PV: plain f16 MFMA, fp32 accumulate; l normalization in f32.
//  * gate fused in epilogue.
// LDS ~45 KB; K/V chunk tiles [32][48] (96B rows: b128-aligned, 2-way banks).
// ---------------------------------------------------------------------------
__global__ __launch_bounds__(256, 2) void attn_kernel(
    const float* __restrict__ q, const float* __restrict__ k, const float* __restrict__ v,
    const float* __restrict__ g, const float* __restrict__ bias_n, float* __restrict__ go)
{
    __shared__ _Float16 Khs[32][48];
    __shared__ _Float16 Kls[32][48];
    __shared__ _Float16 Vts[32][48];     // V^T: [d][kpos_local]
    __shared__ float    Pb[4][64][36];   // per-wave P buffer (f32)

    const int tid  = threadIdx.x;
    const int w    = tid >> 6;
    const int lane = tid & 63;
    const int lg   = lane >> 4, lm = lane & 15;
    const int i = blockIdx.x >> 2, h = blockIdx.x & 3;
    const size_t base = (size_t)i * 256 * 128 + (size_t)h * 32;
    const int j0w = w * 64;

    // ---- Q fragments from global (split f16 hi/lo), resident in regs ----
    f16x8 qh[4], ql[4];
    #pragma unroll
    for (int jt = 0; jt < 4; ++jt) {
        const float* qp = q + base + (size_t)(j0w + jt * 16 + lm) * 128 + lg * 8;
        float4 a = *(const float4*)qp;
        float4 b = *(const float4*)(qp + 4);
        float qv[8] = {a.x, a.y, a.z, a.w, b.x, b.y, b.z, b.w};
        #pragma unroll
        for (int e = 0; e < 8; ++e) {
            _Float16 hh = (_Float16)qv[e];
            qh[jt][e] = hh;
            ql[jt][e] = (_Float16)((qv[e] - (float)hh) * 2048.0f);
        }
    }

    float Oacc[4][2][4] = {};                  // [jt][dt][rr]
    float mrow[4][4], lrow[4][4];              // [jt][rr]
    #pragma unroll
    for (int jt = 0; jt < 4; ++jt)
        #pragma unroll
        for (int rr = 0; rr < 4; ++rr) { mrow[jt][rr] = -1e30f; lrow[jt][rr] = 0.f; }

    for (int kc = 0; kc < 256; kc += 32) {
        // ---- stage K-chunk (split) and V^T-chunk ----
        __syncthreads();
        {
            int r  = tid >> 3;            // kpos-local 0..31
            int c0 = (tid & 7) * 4;       // d col
            float4 kv4 = *(const float4*)(k + base + (size_t)(kc + r) * 128 + c0);
            float kvv[4] = {kv4.x, kv4.y, kv4.z, kv4.w};
            f16x4 h4, l4;
            #pragma unroll
            for (int e = 0; e < 4; ++e) {
                _Float16 hh = (_Float16)kvv[e];
                h4[e] = hh;
                l4[e] = (_Float16)((kvv[e] - (float)hh) * 2048.0f);
            }
            *(f16x4*)&Khs[r][c0] = h4;
            *(f16x4*)&Kls[r][c0] = l4;
            float4 vv4 = *(const float4*)(v + base + (size_t)(kc + r) * 128 + c0);
            Vts[c0 + 0][r] = (_Float16)vv4.x;
            Vts[c0 + 1][r] = (_Float16)vv4.y;
            Vts[c0 + 2][r] = (_Float16)vv4.z;
            Vts[c0 + 3][r] = (_Float16)vv4.w;
        }
        __syncthreads();

        // ---- K/V B-fragments (shared across jt) ----
        f16x8 bh[2], bl[2], vf[2];
        #pragma unroll
        for (int kt = 0; kt < 2; ++kt) {
            bh[kt] = *(const f16x8*)&Khs[kt * 16 + lm][lg * 8];
            bl[kt] = *(const f16x8*)&Kls[kt * 16 + lm][lg * 8];
            vf[kt] = *(const f16x8*)&Vts[kt * 16 + lm][lg * 8];
        }

        // ---- S = bias + QK^T (split f16) ----
        float Sv[4][2][4];
        #pragma unroll
        for (int jt = 0; jt < 4; ++jt) {
            #pragma unroll
            for (int kt = 0; kt < 2; ++kt) {
                const float* bj = bias_n + (size_t)h * NPOS
                                + (size_t)(j0w + jt * 16 + lg * 4) * 256 + kc + kt * 16 + lm;
                f32x4 chi = {bj[0], bj[256], bj[512], bj[768]};
                f32x4 ccr = {0.f, 0.f, 0.f, 0.f};
                chi = __builtin_amdgcn_mfma_f32_16x16x32_f16(qh[jt], bh[kt], chi, 0, 0, 0);
                ccr = __builtin_amdgcn_mfma_f32_16x16x32_f16(ql[jt], bh[kt], ccr, 0, 0, 0);
                ccr = __builtin_amdgcn_mfma_f32_16x16x32_f16(qh[jt], bl[kt], ccr, 0, 0, 0);
                #pragma unroll
                for (int rr = 0; rr < 4; ++rr)
                    Sv[jt][kt][rr] = chi[rr] + ccr[rr] * (1.0f / 2048.0f);
            }
        }

        // ---- online softmax (rows owned by (jt,lg,rr); butterflies over lm) ----
        #pragma unroll
        for (int jt = 0; jt < 4; ++jt) {
            #pragma unroll
            for (int rr = 0; rr < 4; ++rr) {
                float s0 = Sv[jt][0][rr], s1 = Sv[jt][1][rr];
                float mx = fmaxf(s0, s1);
                mx = fmaxf(mx, __shfl_xor(mx, 1));
                mx = fmaxf(mx, __shfl_xor(mx, 2));
                mx = fmaxf(mx, __shfl_xor(mx, 4));
                mx = fmaxf(mx, __shfl_xor(mx, 8));
                float mo = mrow[jt][rr];
                float mn = fmaxf(mo, mx);
                float alpha = __expf(mo - mn);
                mrow[jt][rr] = mn;
                float p0 = __expf(s0 - mn);
                float p1 = __expf(s1 - mn);
                float ps = p0 + p1;
                ps += __shfl_xor(ps, 1);
                ps += __shfl_xor(ps, 2);
                ps += __shfl_xor(ps, 4);
                ps += __shfl_xor(ps, 8);
                lrow[jt][rr] = lrow[jt][rr] * alpha + ps;
                Oacc[jt][0][rr] *= alpha;
                Oacc[jt][1][rr] *= alpha;
                int row = jt * 16 + lg * 4 + rr;
                Pb[w][row][lm]      = p0;
                Pb[w][row][16 + lm] = p1;
            }
        }

        // ---- PV: P (LDS round-trip, f16) @ V^T frags, fp32 accumulate ----
        #pragma unroll
        for (int jt = 0; jt < 4; ++jt) {
            f32x4 pa = *(const f32x4*)&Pb[w][jt * 16 + lm][lg * 8];
            f32x4 pb2 = *(const f32x4*)&Pb[w][jt * 16 + lm][lg * 8 + 4];
            f16x8 pf;
            #pragma unroll
            for (int e = 0; e < 4; ++e) {
                pf[e]     = (_Float16)pa[e];
                pf[e + 4] = (_Float16)pb2[e];
            }
            #pragma unroll
            for (int dt = 0; dt < 2; ++dt) {
                f32x4 c = {Oacc[jt][dt][0], Oacc[jt][dt][1], Oacc[jt][dt][2], Oacc[jt][dt][3]};
                c = __builtin_amdgcn_mfma_f32_16x16x32_f16(pf, vf[dt], c, 0, 0, 0);
                Oacc[jt][dt][0] = c[0]; Oacc[jt][dt][1] = c[1];
                Oacc[jt][dt][2] = c[2]; Oacc[jt][dt][3] = c[3];
            }
        }
    }

    // ---- epilogue: normalize, gate, store ----
    #pragma unroll
    for (int jt = 0; jt < 4; ++jt) {
        #pragma unroll
        for (int rr = 0; rr < 4; ++rr) {
            int j = j0w + jt * 16 + lg * 4 + rr;
            float inv = 1.0f / lrow[jt][rr];
            #pragma unroll
            for (int dt = 0; dt < 2; ++dt) {
                int col = dt * 16 + lm;
                float val = Oacc[jt][dt][rr] * inv;
                float gv = g[base + (size_t)j * 128 + col];
                go[base + (size_t)j * 128 + col] = val * gv;
            }
        }
    }
}

// ---------------------------------------------------------------------------
// Kernel C: out = go @ Wo + bo.  (unchanged; not the bottleneck yet)
// ---------------------------------------------------------------------------
__global__ __launch_bounds__(256) void out_proj_kernel(
    const float* __restrict__ go, const float* __restrict__ Wo, const float* __restrict__ bo,
    float* __restrict__ out)
{
    __shared__ float at[64][140];
    const int tid = threadIdx.x;
    const int p0  = blockIdx.x * 64;

    for (int i = tid; i < 64 * 32; i += 256) {
        int row = i >> 5, c4 = (i & 31) * 4;
        float4 val = *(const float4*)(go + (size_t)(p0 + row) * 128 + c4);
        at[row][c4 + 0] = val.x; at[row][c4 + 1] = val.y;
        at[row][c4 + 2] = val.z; at[row][c4 + 3] = val.w;
    }
    __syncthreads();

    const int ty = tid >> 4, tx = tid & 15;
    float acc[4][8] = {};
    #pragma unroll 2
    for (int kk = 0; kk < 128; ++kk) {
        float4 wA = *(const float4*)(Wo + kk * 128 + tx * 8);
        float4 wB = *(const float4*)(Wo + kk * 128 + tx * 8 + 4);
        #pragma unroll
        for (int rr = 0; rr < 4; ++rr) {
            float av = at[ty * 4 + rr][kk];
            acc[rr][0] = fmaf(av, wA.x, acc[rr][0]);
            acc[rr][1] = fmaf(av, wA.y, acc[rr][1]);
            acc[rr][2] = fmaf(av, wA.z, acc[rr][2]);
            acc[rr][3] = fmaf(av, wA.w, acc[rr][3]);
            acc[rr][4] = fmaf(av, wB.x, acc[rr][4]);
            acc[rr][5] = fmaf(av, wB.y, acc[rr][5]);
            acc[rr][6] = fmaf(av, wB.z, acc[rr][6]);
            acc[rr][7] = fmaf(av, wB.w, acc[rr][7]);
        }
    }
    #pragma unroll
    for (int rr = 0; rr < 4; ++rr) {
        float ov[8];
        #pragma unroll
        for (int c = 0; c < 8; ++c) ov[c] = acc[rr][c] + bo[tx * 8 + c];
        float* outp = out + (size_t)(p0 + ty * 4 + rr) * 128 + tx * 8;
        *(float4*)outp       = *(float4*)ov;
        *(float4*)(outp + 4) = *(float4*)(ov + 4);
    }
}

// ---------------------------------------------------------------------------
extern "C" void kernel_launch(void* const* d_in, const int* in_sizes, int n_in,
                              void* d_out, int out_size, void* d_ws, size_t ws_size,
                              hipStream_t stream) {
    const float* pair = (const float*)d_in[0];
    const float* ln_w = (const float*)d_in[1];
    const float* ln_b = (const float*)d_in[2];
    const float* Wq   = (const float*)d_in[3];
    const float* Wk   = (const float*)d_in[4];
    const float* Wv   = (const float*)d_in[5];
    const float* Wb   = (const float*)d_in[6];
    const float* Wg   = (const float*)d_in[7];
    const float* bg   = (const float*)d_in[8];
    const float* Wo   = (const float*)d_in[9];
    const float* bo   = (const float*)d_in[10];

    // workspace layout (floats): q,k,v,g,go = 65536*128 each; bias_n = 4*65536
    float* ws     = (float*)d_ws;
    float* q      = ws;
    float* k      = ws + (size_t)1 * NPOS * 128;
    float* v      = ws + (size_t)2 * NPOS * 128;
    float* g      = ws + (size_t)3 * NPOS * 128;
    float* go     = ws + (size_t)4 * NPOS * 128;
    float* bias_n = ws + (size_t)5 * NPOS * 128;
    float* out    = (float*)d_out;

    // Transient scratch for pre-split weights: live only during ln_proj,
    // placed in d_out (out_proj overwrites all of d_out at the end).
    _Float16* Wt_hi = (_Float16*)d_out;
    _Float16* Wt_lo = Wt_hi + (size_t)512 * 128;

    hipLaunchKernelGGL(split_w_kernel, dim3(256), dim3(256), 0, stream,
                       Wq, Wk, Wv, Wg, Wt_hi, Wt_lo);
    hipLaunchKernelGGL(ln_proj_kernel, dim3(1024), dim3(256), 0, stream,
                       pair, ln_w, ln_b, Wb, bg, Wt_hi, Wt_lo, q, k, v, g, bias_n);
    hipLaunchKernelGGL(attn_kernel, dim3(1024), dim3(256), 0, stream,
                       q, k, v, g, bias_n, go);
    hipLaunchKernelGGL(out_proj_kernel, dim3(1024), dim3(256), 0, stream,
                       go, Wo, bo, out);
}

// Round 5
// 283.550 us; speedup vs baseline: 1.9530x; 1.2895x over previous
//
#include <hip/hip_runtime.h>
#include <math.h>

// Sizes (hard-coded per reference): B=1, L=256, D=128, H=4, DH=32
// positions P = L*L = 65536; HD = H*DH = 128
#define NPOS 65536

typedef _Float16 f16x8 __attribute__((ext_vector_type(8)));
typedef _Float16 f16x4 __attribute__((ext_vector_type(4)));
typedef float    f32x4 __attribute__((ext_vector_type(4)));

// ---------------------------------------------------------------------------
// Kernel P: split W{q,k,v,g} (fp32, [k=128][n=128] each) into transposed f16
// hi/lo planes: Wt[n_global=512][k=128], n_global = mat*128+n.
// lo is pre-scaled by 2^11 to stay in f16 normal range.
// ---------------------------------------------------------------------------
__global__ __launch_bounds__(256) void split_w_kernel(
    const float* __restrict__ Wq, const float* __restrict__ Wk,
    const float* __restrict__ Wv, const float* __restrict__ Wg,
    _Float16* __restrict__ Wt_hi, _Float16* __restrict__ Wt_lo)
{
    int t = blockIdx.x * 256 + threadIdx.x;       // 0..65535
    int ng = t >> 7, kk = t & 127;
    int mat = ng >> 7, n = ng & 127;
    const float* W = (mat == 0) ? Wq : (mat == 1) ? Wk : (mat == 2) ? Wv : Wg;
    float x = W[kk * 128 + n];
    _Float16 h = (_Float16)x;
    _Float16 lo = (_Float16)((x - (float)h) * 2048.0f);
    Wt_hi[t] = h;
    Wt_lo[t] = lo;
}

// ---------------------------------------------------------------------------
// Kernel A (round-5 rewrite of the MFMA phase): LN + split-f16 MFMA GEMM.
// Round-4 evidence: 160us with MfmaUtil=6%, VALUBusy=7%, HBM=13% -> scatter/
// latency-bound: (a) epilogue stores were 512B-stride scatters (64 lines per
// store instr, ~55us of store-path serialization); (b) B-frags were lane-
// scattered global reads re-sweeping 256KB/wave through L1.
// Fix: (a) B hi/lo chunks (64 N-rows x 128 k) cooperatively staged into LDS
// with contiguous 1KB/instr loads; frags via padded ds_read_b128 (row pitch
// 272B). (b) C-tiles staged through LDS, then coalesced float4 global stores.
// LDS: xh/xl (34816B) reused as B-chunk / output staging after A-frags are
// register-resident -> still 4 blocks/CU.
// ---------------------------------------------------------------------------
__global__ __launch_bounds__(256, 4) void ln_proj_kernel(
    const float* __restrict__ pair, const float* __restrict__ ln_w, const float* __restrict__ ln_b,
    const float* __restrict__ Wb, const float* __restrict__ bg,
    const _Float16* __restrict__ Wt_hi, const _Float16* __restrict__ Wt_lo,
    float* __restrict__ q, float* __restrict__ k, float* __restrict__ v,
    float* __restrict__ g, float* __restrict__ bias_n)
{
    __shared__ _Float16 xbuf[2][64][136];   // phase1: xh/xl; phase2: Bh/Bl; epilogue: staging
    _Float16 (*xh)[136] = xbuf[0];
    _Float16 (*xl)[136] = xbuf[1];

    const int tid = threadIdx.x;
    const int p0  = blockIdx.x * 64;
    const int r   = tid >> 2;          // row 0..63
    const int cb  = (tid & 3) * 32;    // col base (4 threads/row)

    // ---- load 32 pair values (float4) ----
    float xv[32];
    {
        const float4* pr = (const float4*)(pair + (size_t)(p0 + r) * 128 + cb);
        #pragma unroll
        for (int i = 0; i < 8; ++i) {
            float4 t = pr[i];
            xv[i * 4 + 0] = t.x; xv[i * 4 + 1] = t.y;
            xv[i * 4 + 2] = t.z; xv[i * 4 + 3] = t.w;
        }
    }
    // ---- LN stats across the 4 threads of the row ----
    float sum = 0.f, sq = 0.f;
    #pragma unroll
    for (int i = 0; i < 32; ++i) { sum += xv[i]; sq += xv[i] * xv[i]; }
    sum += __shfl_xor(sum, 1); sq += __shfl_xor(sq, 1);
    sum += __shfl_xor(sum, 2); sq += __shfl_xor(sq, 2);
    float mean = sum * (1.f / 128.f);
    float var  = sq * (1.f / 128.f) - mean * mean;
    float rstd = rsqrtf(var + 1e-5f);

    // ---- normalize, split to f16 hi/lo, store to LDS; bias partial dots ----
    float b0 = 0.f, b1 = 0.f, b2 = 0.f, b3 = 0.f;
    #pragma unroll
    for (int i8 = 0; i8 < 4; ++i8) {
        float4 lw0 = *(const float4*)(ln_w + cb + i8 * 8);
        float4 lw1 = *(const float4*)(ln_w + cb + i8 * 8 + 4);
        float4 lb0 = *(const float4*)(ln_b + cb + i8 * 8);
        float4 lb1 = *(const float4*)(ln_b + cb + i8 * 8 + 4);
        float lw[8] = {lw0.x, lw0.y, lw0.z, lw0.w, lw1.x, lw1.y, lw1.z, lw1.w};
        float lb[8] = {lb0.x, lb0.y, lb0.z, lb0.w, lb1.x, lb1.y, lb1.z, lb1.w};
        f16x8 hv, lv;
        #pragma unroll
        for (int j = 0; j < 8; ++j) {
            int i = i8 * 8 + j;
            float xn = (xv[i] - mean) * rstd * lw[j] + lb[j];
            _Float16 h = (_Float16)xn;
            hv[j] = h;
            lv[j] = (_Float16)((xn - (float)h) * 2048.0f);
            float4 wb = *(const float4*)(Wb + (size_t)(cb + i) * 4);
            b0 = fmaf(xn, wb.x, b0); b1 = fmaf(xn, wb.y, b1);
            b2 = fmaf(xn, wb.z, b2); b3 = fmaf(xn, wb.w, b3);
        }
        *(f16x8*)&xh[r][cb + i8 * 8] = hv;
        *(f16x8*)&xl[r][cb + i8 * 8] = lv;
    }
    // reduce bias dots across the 4 threads of the row, store NATURAL layout
    b0 += __shfl_xor(b0, 1); b1 += __shfl_xor(b1, 1);
    b2 += __shfl_xor(b2, 1); b3 += __shfl_xor(b3, 1);
    b0 += __shfl_xor(b0, 2); b1 += __shfl_xor(b1, 2);
    b2 += __shfl_xor(b2, 2); b3 += __shfl_xor(b3, 2);
    if ((tid & 3) == 0) {
        int p = p0 + r;                        // p = j*256 + kpos
        bias_n[0 * NPOS + p] = b0;
        bias_n[1 * NPOS + p] = b1;
        bias_n[2 * NPOS + p] = b2;
        bias_n[3 * NPOS + p] = b3;
    }
    __syncthreads();

    // ---- A fragments -> registers (16 rows per wave, full K=128) ----
    const int w  = tid >> 6, l = tid & 63;
    const int lm = l & 15, lg = l >> 4;
    const int arow = w * 16 + lm;

    f16x8 ahf[4], alf[4];
    #pragma unroll
    for (int kt = 0; kt < 4; ++kt) {
        ahf[kt] = *(const f16x8*)&xh[arow][kt * 32 + lg * 8];
        alf[kt] = *(const f16x8*)&xl[arow][kt * 32 + lg * 8];
    }

    // Aliases for phase-2 reuse of the same LDS
    _Float16 (*Bh)[136] = xbuf[0];
    _Float16 (*Bl)[136] = xbuf[1];
    float* stg = (float*)&xbuf[0][0][0];      // [64][68] f32 = 17408 B

    const float scale = 0.17677669529663687f;  // 1/sqrt(32)

    for (int chunk = 0; chunk < 8; ++chunk) {
        const int mat = chunk >> 1;            // 0:q 1:k 2:v 3:g
        const int colhalf = (chunk & 1) * 64;
        float* dst = (mat == 0) ? q : (mat == 1) ? k : (mat == 2) ? v : g;

        // ---- sync: A-frag reads (chunk 0) / previous coop-store reads done
        __syncthreads();

        // ---- cooperative B-chunk load: 64 N-rows x 128 k, hi+lo (contig 1KB/instr)
        {
            const _Float16* srch = Wt_hi + (size_t)(chunk * 64) * 128;
            const _Float16* srcl = Wt_lo + (size_t)(chunk * 64) * 128;
            #pragma unroll
            for (int it = 0; it < 4; ++it) {
                int idx = it * 256 + tid;
                int row = idx >> 4, kc8 = (idx & 15) * 8;
                *(f16x8*)&Bh[row][kc8] = *(const f16x8*)(srch + row * 128 + kc8);
                *(f16x8*)&Bl[row][kc8] = *(const f16x8*)(srcl + row * 128 + kc8);
            }
        }
        __syncthreads();

        // ---- MFMA: 4 col-tiles x 4 kt x 3 (split) ----
        f32x4 acch[4], accc[4];
        #pragma unroll
        for (int ct = 0; ct < 4; ++ct) {
            acch[ct] = (f32x4){0.f, 0.f, 0.f, 0.f};
            accc[ct] = (f32x4){0.f, 0.f, 0.f, 0.f};
        }
        #pragma unroll
        for (int kt = 0; kt < 4; ++kt) {
            const int koff = kt * 32 + lg * 8;
            #pragma unroll
            for (int ct = 0; ct < 4; ++ct) {
                f16x8 bh = *(const f16x8*)&Bh[ct * 16 + lm][koff];
                f16x8 bl = *(const f16x8*)&Bl[ct * 16 + lm][koff];
                acch[ct] = __builtin_amdgcn_mfma_f32_16x16x32_f16(ahf[kt], bh, acch[ct], 0, 0, 0);
                accc[ct] = __builtin_amdgcn_mfma_f32_16x16x32_f16(alf[kt], bh, accc[ct], 0, 0, 0);
                accc[ct] = __builtin_amdgcn_mfma_f32_16x16x32_f16(ahf[kt], bl, accc[ct], 0, 0, 0);
            }
        }

        // ---- sync: all frag reads done before staging overwrites Bh ----
        __syncthreads();

        // ---- epilogue math + stage C-tile in LDS [64][68] ----
        #pragma unroll
        for (int ct = 0; ct < 4; ++ct) {
            const int col = ct * 16 + lm;
            float bgv = (mat == 3) ? bg[colhalf + col] : 0.f;
            #pragma unroll
            for (int rr = 0; rr < 4; ++rr) {
                float val = acch[ct][rr] + accc[ct][rr] * (1.0f / 2048.0f);
                if (mat == 0) val *= scale;
                if (mat == 3) val = 1.f / (1.f + __expf(-(val + bgv)));
                stg[(w * 16 + lg * 4 + rr) * 68 + col] = val;
            }
        }
        __syncthreads();

        // ---- coalesced store: rows of 64 floats (256B runs) ----
        #pragma unroll
        for (int it = 0; it < 4; ++it) {
            int idx = it * 256 + tid;
            int row = idx >> 4, c4 = (idx & 15) * 4;
            float4 val = *(const float4*)&stg[row * 68 + c4];
            *(float4*)(dst + (size_t)(p0 + row) * 128 + colhalf + c4) = val;
        }
    }
}

// ---------------------------------------------------------------------------
// Kernel B: MFMA flash attention. One block per (i,h), 4 waves x 64 j-rows,
// chunks of 32 kpos. (unchanged this round)
// ---------------------------------------------------------------------------
__global__ __launch_bounds__(256, 2) void attn_kernel(
    const float* __restrict__ q, const float* __restrict__ k, const float* __restrict__ v,
    const float* __restrict__ g, const float* __restrict__ bias_n, float* __restrict__ go)
{
    __shared__ _Float16 Khs[32][48];
    __shared__ _Float16 Kls[32][48];
    __shared__ _Float16 Vts[32][48];     // V^T: [d][kpos_local]
    __shared__ float    Pb[4][64][36];   // per-wave P buffer (f32)

    const int tid  = threadIdx.x;
    const int w    = tid >> 6;
    const int lane = tid & 63;
    const int lg   = lane >> 4, lm = lane & 15;
    const int i = blockIdx.x >> 2, h = blockIdx.x & 3;
    const size_t base = (size_t)i * 256 * 128 + (size_t)h * 32;
    const int j0w = w * 64;

    // ---- Q fragments from global (split f16 hi/lo), resident in regs ----
    f16x8 qh[4], ql[4];
    #pragma unroll
    for (int jt = 0; jt < 4; ++jt) {
        const float* qp = q + base + (size_t)(j0w + jt * 16 + lm) * 128 + lg * 8;
        float4 a = *(const float4*)qp;
        float4 b = *(const float4*)(qp + 4);
        float qv[8] = {a.x, a.y, a.z, a.w, b.x, b.y, b.z, b.w};
        #pragma unroll
        for (int e = 0; e < 8; ++e) {
            _Float16 hh = (_Float16)qv[e];
            qh[jt][e] = hh;
            ql[jt][e] = (_Float16)((qv[e] - (float)hh) * 2048.0f);
        }
    }

    float Oacc[4][2][4] = {};                  // [jt][dt][rr]
    float mrow[4][4], lrow[4][4];              // [jt][rr]
    #pragma unroll
    for (int jt = 0; jt < 4; ++jt)
        #pragma unroll
        for (int rr = 0; rr < 4; ++rr) { mrow[jt][rr] = -1e30f; lrow[jt][rr] = 0.f; }

    for (int kc = 0; kc < 256; kc += 32) {
        // ---- stage K-chunk (split) and V^T-chunk ----
        __syncthreads();
        {
            int r  = tid >> 3;            // kpos-local 0..31
            int c0 = (tid & 7) * 4;       // d col
            float4 kv4 = *(const float4*)(k + base + (size_t)(kc + r) * 128 + c0);
            float kvv[4] = {kv4.x, kv4.y, kv4.z, kv4.w};
            f16x4 h4, l4;
            #pragma unroll
            for (int e = 0; e < 4; ++e) {
                _Float16 hh = (_Float16)kvv[e];
                h4[e] = hh;
                l4[e] = (_Float16)((kvv[e] - (float)hh) * 2048.0f);
            }
            *(f16x4*)&Khs[r][c0] = h4;
            *(f16x4*)&Kls[r][c0] = l4;
            float4 vv4 = *(const float4*)(v + base + (size_t)(kc + r) * 128 + c0);
            Vts[c0 + 0][r] = (_Float16)vv4.x;
            Vts[c0 + 1][r] = (_Float16)vv4.y;
            Vts[c0 + 2][r] = (_Float16)vv4.z;
            Vts[c0 + 3][r] = (_Float16)vv4.w;
        }
        __syncthreads();

        // ---- K/V B-fragments (shared across jt) ----
        f16x8 bh[2], bl[2], vf[2];
        #pragma unroll
        for (int kt = 0; kt < 2; ++kt) {
            bh[kt] = *(const f16x8*)&Khs[kt * 16 + lm][lg * 8];
            bl[kt] = *(const f16x8*)&Kls[kt * 16 + lm][lg * 8];
            vf[kt] = *(const f16x8*)&Vts[kt * 16 + lm][lg * 8];
        }

        // ---- S = bias + QK^T (split f16) ----
        float Sv[4][2][4];
        #pragma unroll
        for (int jt = 0; jt < 4; ++jt) {
            #pragma unroll
            for (int kt = 0; kt < 2; ++kt) {
                const float* bj = bias_n + (size_t)h * NPOS
                                + (size_t)(j0w + jt * 16 + lg * 4) * 256 + kc + kt * 16 + lm;
                f32x4 chi = {bj[0], bj[256], bj[512], bj[768]};
                f32x4 ccr = {0.f, 0.f, 0.f, 0.f};
                chi = __builtin_amdgcn_mfma_f32_16x16x32_f16(qh[jt], bh[kt], chi, 0, 0, 0);
                ccr = __builtin_amdgcn_mfma_f32_16x16x32_f16(ql[jt], bh[kt], ccr, 0, 0, 0);
                ccr = __builtin_amdgcn_mfma_f32_16x16x32_f16(qh[jt], bl[kt], ccr, 0, 0, 0);
                #pragma unroll
                for (int rr = 0; rr < 4; ++rr)
                    Sv[jt][kt][rr] = chi[rr] + ccr[rr] * (1.0f / 2048.0f);
            }
        }

        // ---- online softmax (rows owned by (jt,lg,rr); butterflies over lm) ----
        #pragma unroll
        for (int jt = 0; jt < 4; ++jt) {
            #pragma unroll
            for (int rr = 0; rr < 4; ++rr) {
                float s0 = Sv[jt][0][rr], s1 = Sv[jt][1][rr];
                float mx = fmaxf(s0, s1);
                mx = fmaxf(mx, __shfl_xor(mx, 1));
                mx = fmaxf(mx, __shfl_xor(mx, 2));
                mx = fmaxf(mx, __shfl_xor(mx, 4));
                mx = fmaxf(mx, __shfl_xor(mx, 8));
                float mo = mrow[jt][rr];
                float mn = fmaxf(mo, mx);
                float alpha = __expf(mo - mn);
                mrow[jt][rr] = mn;
                float p0 = __expf(s0 - mn);
                float p1 = __expf(s1 - mn);
                float ps = p0 + p1;
                ps += __shfl_xor(ps, 1);
                ps += __shfl_xor(ps, 2);
                ps += __shfl_xor(ps, 4);
                ps += __shfl_xor(ps, 8);
                lrow[jt][rr] = lrow[jt][rr] * alpha + ps;
                Oacc[jt][0][rr] *= alpha;
                Oacc[jt][1][rr] *= alpha;
                int row = jt * 16 + lg * 4 + rr;
                Pb[w][row][lm]      = p0;
                Pb[w][row][16 + lm] = p1;
            }
        }

        // ---- PV: P (LDS round-trip, f16) @ V^T frags, fp32 accumulate ----
        #pragma unroll
        for (int jt = 0; jt < 4; ++jt) {
            f32x4 pa = *(const f32x4*)&Pb[w][jt * 16 + lm][lg * 8];
            f32x4 pb2 = *(const f32x4*)&Pb[w][jt * 16 + lm][lg * 8 + 4];
            f16x8 pf;
            #pragma unroll
            for (int e = 0; e < 4; ++e) {
                pf[e]     = (_Float16)pa[e];
                pf[e + 4] = (_Float16)pb2[e];
            }
            #pragma unroll
            for (int dt = 0; dt < 2; ++dt) {
                f32x4 c = {Oacc[jt][dt][0], Oacc[jt][dt][1], Oacc[jt][dt][2], Oacc[jt][dt][3]};
                c = __builtin_amdgcn_mfma_f32_16x16x32_f16(pf, vf[dt], c, 0, 0, 0);
                Oacc[jt][dt][0] = c[0]; Oacc[jt][dt][1] = c[1];
                Oacc[jt][dt][2] = c[2]; Oacc[jt][dt][3] = c[3];
            }
        }
    }

    // ---- epilogue: normalize, gate, store ----
    #pragma unroll
    for (int jt = 0; jt < 4; ++jt) {
        #pragma unroll
        for (int rr = 0; rr < 4; ++rr) {
            int j = j0w + jt * 16 + lg * 4 + rr;
            float inv = 1.0f / lrow[jt][rr];
            #pragma unroll
            for (int dt = 0; dt < 2; ++dt) {
                int col = dt * 16 + lm;
                float val = Oacc[jt][dt][rr] * inv;
                float gv = g[base + (size_t)j * 128 + col];
                go[base + (size_t)j * 128 + col] = val * gv;
            }
        }
    }
}

// ---------------------------------------------------------------------------
// Kernel C: out = go @ Wo + bo.  (unchanged; not the bottleneck yet)
// ---------------------------------------------------------------------------
__global__ __launch_bounds__(256) void out_proj_kernel(
    const float* __restrict__ go, const float* __restrict__ Wo, const float* __restrict__ bo,
    float* __restrict__ out)
{
    __shared__ float at[64][140];
    const int tid = threadIdx.x;
    const int p0  = blockIdx.x * 64;

    for (int i = tid; i < 64 * 32; i += 256) {
        int row = i >> 5, c4 = (i & 31) * 4;
        float4 val = *(const float4*)(go + (size_t)(p0 + row) * 128 + c4);
        at[row][c4 + 0] = val.x; at[row][c4 + 1] = val.y;
        at[row][c4 + 2] = val.z; at[row][c4 + 3] = val.w;
    }
    __syncthreads();

    const int ty = tid >> 4, tx = tid & 15;
    float acc[4][8] = {};
    #pragma unroll 2
    for (int kk = 0; kk < 128; ++kk) {
        float4 wA = *(const float4*)(Wo + kk * 128 + tx * 8);
        float4 wB = *(const float4*)(Wo + kk * 128 + tx * 8 + 4);
        #pragma unroll
        for (int rr = 0; rr < 4; ++rr) {
            float av = at[ty * 4 + rr][kk];
            acc[rr][0] = fmaf(av, wA.x, acc[rr][0]);
            acc[rr][1] = fmaf(av, wA.y, acc[rr][1]);
            acc[rr][2] = fmaf(av, wA.z, acc[rr][2]);
            acc[rr][3] = fmaf(av, wA.w, acc[rr][3]);
            acc[rr][4] = fmaf(av, wB.x, acc[rr][4]);
            acc[rr][5] = fmaf(av, wB.y, acc[rr][5]);
            acc[rr][6] = fmaf(av, wB.z, acc[rr][6]);
            acc[rr][7] = fmaf(av, wB.w, acc[rr][7]);
        }
    }
    #pragma unroll
    for (int rr = 0; rr < 4; ++rr) {
        float ov[8];
        #pragma unroll
        for (int c = 0; c < 8; ++c) ov[c] = acc[rr][c] + bo[tx * 8 + c];
        float* outp = out + (size_t)(p0 + ty * 4 + rr) * 128 + tx * 8;
        *(float4*)outp       = *(float4*)ov;
        *(float4*)(outp + 4) = *(float4*)(ov + 4);
    }
}

// ---------------------------------------------------------------------------
extern "C" void kernel_launch(void* const* d_in, const int* in_sizes, int n_in,
                              void* d_out, int out_size, void* d_ws, size_t ws_size,
                              hipStream_t stream) {
    const float* pair = (const float*)d_in[0];
    const float* ln_w = (const float*)d_in[1];
    const float* ln_b = (const float*)d_in[2];
    const float* Wq   = (const float*)d_in[3];
    const float* Wk   = (const float*)d_in[4];
    const float* Wv   = (const float*)d_in[5];
    const float* Wb   = (const float*)d_in[6];
    const float* Wg   = (const float*)d_in[7];
    const float* bg   = (const float*)d_in[8];
    const float* Wo   = (const float*)d_in[9];
    const float* bo   = (const float*)d_in[10];

    // workspace layout (floats): q,k,v,g,go = 65536*128 each; bias_n = 4*65536
    float* ws     = (float*)d_ws;
    float* q      = ws;
    float* k      = ws + (size_t)1 * NPOS * 128;
    float* v      = ws + (size_t)2 * NPOS * 128;
    float* g      = ws + (size_t)3 * NPOS * 128;
    float* go     = ws + (size_t)4 * NPOS * 128;
    float* bias_n = ws + (size_t)5 * NPOS * 128;
    float* out    = (float*)d_out;

    // Transient scratch for pre-split weights: live only during ln_proj,
    // placed in d_out (out_proj overwrites all of d_out at the end).
    _Float16* Wt_hi = (_Float16*)d_out;
    _Float16* Wt_lo = Wt_hi + (size_t)512 * 128;

    hipLaunchKernelGGL(split_w_kernel, dim3(256), dim3(256), 0, stream,
                       Wq, Wk, Wv, Wg, Wt_hi, Wt_lo);
    hipLaunchKernelGGL(ln_proj_kernel, dim3(1024), dim3(256), 0, stream,
                       pair, ln_w, ln_b, Wb, bg, Wt_hi, Wt_lo, q, k, v, g, bias_n);
    hipLaunchKernelGGL(attn_kernel, dim3(1024), dim3(256), 0, stream,
                       q, k, v, g, bias_n, go);
    hipLaunchKernelGGL(out_proj_kernel, dim3(1024), dim3(256), 0, stream,
                       go, Wo, bo, out);
}

// Round 6
// 263.992 us; speedup vs baseline: 2.0977x; 1.0741x over previous
//
#include <hip/hip_runtime.h>
#include <math.h>

// Sizes (hard-coded per reference): B=1, L=256, D=128, H=4, DH=32
// positions P = L*L = 65536; HD = H*DH = 128
#define NPOS 65536

typedef _Float16 f16x8 __attribute__((ext_vector_type(8)));
typedef _Float16 f16x4 __attribute__((ext_vector_type(4)));
typedef float    f32x4 __attribute__((ext_vector_type(4)));

// ---------------------------------------------------------------------------
// Kernel P: split W{q,k,v,g} (fp32, [k=128][n=128] each) into transposed f16
// hi/lo planes: Wt[n_global=512][k=128], n_global = mat*128+n.
// lo is pre-scaled by 2^11 to stay in f16 normal range.
// ---------------------------------------------------------------------------
__global__ __launch_bounds__(256) void split_w_kernel(
    const float* __restrict__ Wq, const float* __restrict__ Wk,
    const float* __restrict__ Wv, const float* __restrict__ Wg,
    _Float16* __restrict__ Wt_hi, _Float16* __restrict__ Wt_lo)
{
    int t = blockIdx.x * 256 + threadIdx.x;       // 0..65535
    int ng = t >> 7, kk = t & 127;
    int mat = ng >> 7, n = ng & 127;
    const float* W = (mat == 0) ? Wq : (mat == 1) ? Wk : (mat == 2) ? Wv : Wg;
    float x = W[kk * 128 + n];
    _Float16 h = (_Float16)x;
    _Float16 lo = (_Float16)((x - (float)h) * 2048.0f);
    Wt_hi[t] = h;
    Wt_lo[t] = lo;
}

// ---------------------------------------------------------------------------
// Kernel A: LN + split-f16 MFMA GEMM (unchanged this round).
// ---------------------------------------------------------------------------
__global__ __launch_bounds__(256, 4) void ln_proj_kernel(
    const float* __restrict__ pair, const float* __restrict__ ln_w, const float* __restrict__ ln_b,
    const float* __restrict__ Wb, const float* __restrict__ bg,
    const _Float16* __restrict__ Wt_hi, const _Float16* __restrict__ Wt_lo,
    float* __restrict__ q, float* __restrict__ k, float* __restrict__ v,
    float* __restrict__ g, float* __restrict__ bias_n)
{
    __shared__ _Float16 xbuf[2][64][136];   // phase1: xh/xl; phase2: Bh/Bl; epilogue: staging
    _Float16 (*xh)[136] = xbuf[0];
    _Float16 (*xl)[136] = xbuf[1];

    const int tid = threadIdx.x;
    const int p0  = blockIdx.x * 64;
    const int r   = tid >> 2;          // row 0..63
    const int cb  = (tid & 3) * 32;    // col base (4 threads/row)

    // ---- load 32 pair values (float4) ----
    float xv[32];
    {
        const float4* pr = (const float4*)(pair + (size_t)(p0 + r) * 128 + cb);
        #pragma unroll
        for (int i = 0; i < 8; ++i) {
            float4 t = pr[i];
            xv[i * 4 + 0] = t.x; xv[i * 4 + 1] = t.y;
            xv[i * 4 + 2] = t.z; xv[i * 4 + 3] = t.w;
        }
    }
    // ---- LN stats across the 4 threads of the row ----
    float sum = 0.f, sq = 0.f;
    #pragma unroll
    for (int i = 0; i < 32; ++i) { sum += xv[i]; sq += xv[i] * xv[i]; }
    sum += __shfl_xor(sum, 1); sq += __shfl_xor(sq, 1);
    sum += __shfl_xor(sum, 2); sq += __shfl_xor(sq, 2);
    float mean = sum * (1.f / 128.f);
    float var  = sq * (1.f / 128.f) - mean * mean;
    float rstd = rsqrtf(var + 1e-5f);

    // ---- normalize, split to f16 hi/lo, store to LDS; bias partial dots ----
    float b0 = 0.f, b1 = 0.f, b2 = 0.f, b3 = 0.f;
    #pragma unroll
    for (int i8 = 0; i8 < 4; ++i8) {
        float4 lw0 = *(const float4*)(ln_w + cb + i8 * 8);
        float4 lw1 = *(const float4*)(ln_w + cb + i8 * 8 + 4);
        float4 lb0 = *(const float4*)(ln_b + cb + i8 * 8);
        float4 lb1 = *(const float4*)(ln_b + cb + i8 * 8 + 4);
        float lw[8] = {lw0.x, lw0.y, lw0.z, lw0.w, lw1.x, lw1.y, lw1.z, lw1.w};
        float lb[8] = {lb0.x, lb0.y, lb0.z, lb0.w, lb1.x, lb1.y, lb1.z, lb1.w};
        f16x8 hv, lv;
        #pragma unroll
        for (int j = 0; j < 8; ++j) {
            int i = i8 * 8 + j;
            float xn = (xv[i] - mean) * rstd * lw[j] + lb[j];
            _Float16 h = (_Float16)xn;
            hv[j] = h;
            lv[j] = (_Float16)((xn - (float)h) * 2048.0f);
            float4 wb = *(const float4*)(Wb + (size_t)(cb + i) * 4);
            b0 = fmaf(xn, wb.x, b0); b1 = fmaf(xn, wb.y, b1);
            b2 = fmaf(xn, wb.z, b2); b3 = fmaf(xn, wb.w, b3);
        }
        *(f16x8*)&xh[r][cb + i8 * 8] = hv;
        *(f16x8*)&xl[r][cb + i8 * 8] = lv;
    }
    // reduce bias dots across the 4 threads of the row, store NATURAL layout
    b0 += __shfl_xor(b0, 1); b1 += __shfl_xor(b1, 1);
    b2 += __shfl_xor(b2, 1); b3 += __shfl_xor(b3, 1);
    b0 += __shfl_xor(b0, 2); b1 += __shfl_xor(b1, 2);
    b2 += __shfl_xor(b2, 2); b3 += __shfl_xor(b3, 2);
    if ((tid & 3) == 0) {
        int p = p0 + r;                        // p = j*256 + kpos
        bias_n[0 * NPOS + p] = b0;
        bias_n[1 * NPOS + p] = b1;
        bias_n[2 * NPOS + p] = b2;
        bias_n[3 * NPOS + p] = b3;
    }
    __syncthreads();

    // ---- A fragments -> registers (16 rows per wave, full K=128) ----
    const int w  = tid >> 6, l = tid & 63;
    const int lm = l & 15, lg = l >> 4;
    const int arow = w * 16 + lm;

    f16x8 ahf[4], alf[4];
    #pragma unroll
    for (int kt = 0; kt < 4; ++kt) {
        ahf[kt] = *(const f16x8*)&xh[arow][kt * 32 + lg * 8];
        alf[kt] = *(const f16x8*)&xl[arow][kt * 32 + lg * 8];
    }

    // Aliases for phase-2 reuse of the same LDS
    _Float16 (*Bh)[136] = xbuf[0];
    _Float16 (*Bl)[136] = xbuf[1];
    float* stg = (float*)&xbuf[0][0][0];      // [64][68] f32 = 17408 B

    const float scale = 0.17677669529663687f;  // 1/sqrt(32)

    for (int chunk = 0; chunk < 8; ++chunk) {
        const int mat = chunk >> 1;            // 0:q 1:k 2:v 3:g
        const int colhalf = (chunk & 1) * 64;
        float* dst = (mat == 0) ? q : (mat == 1) ? k : (mat == 2) ? v : g;

        // ---- sync: A-frag reads (chunk 0) / previous coop-store reads done
        __syncthreads();

        // ---- cooperative B-chunk load: 64 N-rows x 128 k, hi+lo (contig 1KB/instr)
        {
            const _Float16* srch = Wt_hi + (size_t)(chunk * 64) * 128;
            const _Float16* srcl = Wt_lo + (size_t)(chunk * 64) * 128;
            #pragma unroll
            for (int it = 0; it < 4; ++it) {
                int idx = it * 256 + tid;
                int row = idx >> 4, kc8 = (idx & 15) * 8;
                *(f16x8*)&Bh[row][kc8] = *(const f16x8*)(srch + row * 128 + kc8);
                *(f16x8*)&Bl[row][kc8] = *(const f16x8*)(srcl + row * 128 + kc8);
            }
        }
        __syncthreads();

        // ---- MFMA: 4 col-tiles x 4 kt x 3 (split) ----
        f32x4 acch[4], accc[4];
        #pragma unroll
        for (int ct = 0; ct < 4; ++ct) {
            acch[ct] = (f32x4){0.f, 0.f, 0.f, 0.f};
            accc[ct] = (f32x4){0.f, 0.f, 0.f, 0.f};
        }
        #pragma unroll
        for (int kt = 0; kt < 4; ++kt) {
            const int koff = kt * 32 + lg * 8;
            #pragma unroll
            for (int ct = 0; ct < 4; ++ct) {
                f16x8 bh = *(const f16x8*)&Bh[ct * 16 + lm][koff];
                f16x8 bl = *(const f16x8*)&Bl[ct * 16 + lm][koff];
                acch[ct] = __builtin_amdgcn_mfma_f32_16x16x32_f16(ahf[kt], bh, acch[ct], 0, 0, 0);
                accc[ct] = __builtin_amdgcn_mfma_f32_16x16x32_f16(alf[kt], bh, accc[ct], 0, 0, 0);
                accc[ct] = __builtin_amdgcn_mfma_f32_16x16x32_f16(ahf[kt], bl, accc[ct], 0, 0, 0);
            }
        }

        // ---- sync: all frag reads done before staging overwrites Bh ----
        __syncthreads();

        // ---- epilogue math + stage C-tile in LDS [64][68] ----
        #pragma unroll
        for (int ct = 0; ct < 4; ++ct) {
            const int col = ct * 16 + lm;
            float bgv = (mat == 3) ? bg[colhalf + col] : 0.f;
            #pragma unroll
            for (int rr = 0; rr < 4; ++rr) {
                float val = acch[ct][rr] + accc[ct][rr] * (1.0f / 2048.0f);
                if (mat == 0) val *= scale;
                if (mat == 3) val = 1.f / (1.f + __expf(-(val + bgv)));
                stg[(w * 16 + lg * 4 + rr) * 68 + col] = val;
            }
        }
        __syncthreads();

        // ---- coalesced store: rows of 64 floats (256B runs) ----
        #pragma unroll
        for (int it = 0; it < 4; ++it) {
            int idx = it * 256 + tid;
            int row = idx >> 4, c4 = (idx & 15) * 4;
            float4 val = *(const float4*)&stg[row * 68 + c4];
            *(float4*)(dst + (size_t)(p0 + row) * 128 + colhalf + c4) = val;
        }
    }
}

// ---------------------------------------------------------------------------
// Kernel B (round-6 rewrite): S^T-form MFMA flash attention.
// Round-5 evidence: 93us, MfmaUtil 7%, VALUBusy 34%, no pipe saturated ->
// softmax shuffle chains (128 DS-shuffles/chunk/wave, k spread across lanes)
// + scalar bias loads + f32 P round-trip, on 2 waves/SIMD of latency cover.
// Fix: compute S^T = K*Q^T (operand swap; frag layouts are symmetric), so
// each lane owns 8 consecutive k-scores in REGISTERS for one j:
//  * softmax: 7 in-reg ops + 2 shuffles (xor16,32) per jt -> 16 shuf/chunk.
//  * bias C-init: contiguous float4 (k is the reg dim now).
//  * P written f16 (2 ds_write_b64/jt) into per-wave Pb[j][k]; read back as
//    B-operand of O^T = V^T * P^T (V^T frag read identical to before).
//  * O^T C-layout col = j = lm -> alpha/l/gate all lane-local, float4 I/O.
//  * K/V global loads prefetched one chunk ahead; K-tile pitch 56 (2-way);
//    LDS 31KB, __launch_bounds__(256,3) -> 3 blocks/CU.
// ---------------------------------------------------------------------------
__global__ __launch_bounds__(256, 3) void attn_kernel(
    const float* __restrict__ q, const float* __restrict__ k, const float* __restrict__ v,
    const float* __restrict__ g, const float* __restrict__ bias_n, float* __restrict__ go)
{
    __shared__ _Float16 Khs[32][56];
    __shared__ _Float16 Kls[32][56];
    __shared__ _Float16 Vts[32][56];     // V^T: [d][kpos_local]
    __shared__ _Float16 Pb[4][64][40];   // per-wave P[j][k] f16 (pitch 80B)

    const int tid  = threadIdx.x;
    const int w    = tid >> 6;
    const int lane = tid & 63;
    const int lg   = lane >> 4, lm = lane & 15;
    const int i = blockIdx.x >> 2, h = blockIdx.x & 3;
    const size_t base = (size_t)i * 256 * 128 + (size_t)h * 32;
    const int j0w = w * 64;

    // Q fragments (split f16 hi/lo); B-operand of S^T: B[k=d][n=j], lane lm=j.
    f16x8 qh[4], ql[4];
    #pragma unroll
    for (int jt = 0; jt < 4; ++jt) {
        const float* qp = q + base + (size_t)(j0w + jt * 16 + lm) * 128 + lg * 8;
        float4 a = *(const float4*)qp;
        float4 b = *(const float4*)(qp + 4);
        float qv[8] = {a.x, a.y, a.z, a.w, b.x, b.y, b.z, b.w};
        #pragma unroll
        for (int e = 0; e < 8; ++e) {
            _Float16 hh = (_Float16)qv[e];
            qh[jt][e] = hh;
            ql[jt][e] = (_Float16)((qv[e] - (float)hh) * 2048.0f);
        }
    }

    float Oacc[2][4][4] = {};            // [dt][jt][rr]: O^T (col=j=lm, row=d)
    float mrow[4], lrow[4];
    #pragma unroll
    for (int jt = 0; jt < 4; ++jt) { mrow[jt] = -1e30f; lrow[jt] = 0.f; }

    const int sr  = tid >> 3;            // staging kpos-local 0..31
    const int sc0 = (tid & 7) * 4;       // staging d col

    float4 kpre = *(const float4*)(k + base + (size_t)sr * 128 + sc0);
    float4 vpre = *(const float4*)(v + base + (size_t)sr * 128 + sc0);

    for (int kc = 0; kc < 256; kc += 32) {
        __syncthreads();
        {
            float kvv[4] = {kpre.x, kpre.y, kpre.z, kpre.w};
            f16x4 h4, l4;
            #pragma unroll
            for (int e = 0; e < 4; ++e) {
                _Float16 hh = (_Float16)kvv[e];
                h4[e] = hh;
                l4[e] = (_Float16)((kvv[e] - (float)hh) * 2048.0f);
            }
            *(f16x4*)&Khs[sr][sc0] = h4;
            *(f16x4*)&Kls[sr][sc0] = l4;
            Vts[sc0 + 0][sr] = (_Float16)vpre.x;
            Vts[sc0 + 1][sr] = (_Float16)vpre.y;
            Vts[sc0 + 2][sr] = (_Float16)vpre.z;
            Vts[sc0 + 3][sr] = (_Float16)vpre.w;
        }
        __syncthreads();
        if (kc + 32 < 256) {              // prefetch next chunk (overlaps compute)
            kpre = *(const float4*)(k + base + (size_t)(kc + 32 + sr) * 128 + sc0);
            vpre = *(const float4*)(v + base + (size_t)(kc + 32 + sr) * 128 + sc0);
        }

        // A-operand frags: K (lane lm = kpos), V^T (lane lm = d)
        f16x8 bh[2], bl[2], vf[2];
        #pragma unroll
        for (int kt = 0; kt < 2; ++kt) {
            bh[kt] = *(const f16x8*)&Khs[kt * 16 + lm][lg * 8];
            bl[kt] = *(const f16x8*)&Kls[kt * 16 + lm][lg * 8];
            vf[kt] = *(const f16x8*)&Vts[kt * 16 + lm][lg * 8];
        }

        // ---- per j-tile: S^T, softmax (reg-local k), P write ----
        #pragma unroll
        for (int jt = 0; jt < 4; ++jt) {
            const float* bj = bias_n + (size_t)h * NPOS
                            + (size_t)(j0w + jt * 16 + lm) * 256 + kc + lg * 4;
            float4 b0 = *(const float4*)bj;
            float4 b1 = *(const float4*)(bj + 16);
            f32x4 c0h = {b0.x, b0.y, b0.z, b0.w};
            f32x4 c1h = {b1.x, b1.y, b1.z, b1.w};
            f32x4 c0l = {0.f, 0.f, 0.f, 0.f}, c1l = {0.f, 0.f, 0.f, 0.f};
            c0h = __builtin_amdgcn_mfma_f32_16x16x32_f16(bh[0], qh[jt], c0h, 0, 0, 0);
            c0l = __builtin_amdgcn_mfma_f32_16x16x32_f16(bl[0], qh[jt], c0l, 0, 0, 0);
            c0l = __builtin_amdgcn_mfma_f32_16x16x32_f16(bh[0], ql[jt], c0l, 0, 0, 0);
            c1h = __builtin_amdgcn_mfma_f32_16x16x32_f16(bh[1], qh[jt], c1h, 0, 0, 0);
            c1l = __builtin_amdgcn_mfma_f32_16x16x32_f16(bl[1], qh[jt], c1l, 0, 0, 0);
            c1l = __builtin_amdgcn_mfma_f32_16x16x32_f16(bh[1], ql[jt], c1l, 0, 0, 0);

            float s[8];
            #pragma unroll
            for (int rr = 0; rr < 4; ++rr) {
                s[rr]     = c0h[rr] + c0l[rr] * (1.0f / 2048.0f);
                s[4 + rr] = c1h[rr] + c1l[rr] * (1.0f / 2048.0f);
            }
            float mx = s[0];
            #pragma unroll
            for (int e = 1; e < 8; ++e) mx = fmaxf(mx, s[e]);
            mx = fmaxf(mx, __shfl_xor(mx, 16));
            mx = fmaxf(mx, __shfl_xor(mx, 32));
            float mn = fmaxf(mrow[jt], mx);
            float alpha = __expf(mrow[jt] - mn);
            mrow[jt] = mn;
            float p[8], ps = 0.f;
            #pragma unroll
            for (int e = 0; e < 8; ++e) { p[e] = __expf(s[e] - mn); ps += p[e]; }
            ps += __shfl_xor(ps, 16);
            ps += __shfl_xor(ps, 32);
            lrow[jt] = lrow[jt] * alpha + ps;
            #pragma unroll
            for (int dt = 0; dt < 2; ++dt)
                #pragma unroll
                for (int rr = 0; rr < 4; ++rr) Oacc[dt][jt][rr] *= alpha;
            f16x4 pa, pbv;
            #pragma unroll
            for (int rr = 0; rr < 4; ++rr) { pa[rr] = (_Float16)p[rr]; pbv[rr] = (_Float16)p[4 + rr]; }
            *(f16x4*)&Pb[w][jt * 16 + lm][lg * 4]      = pa;
            *(f16x4*)&Pb[w][jt * 16 + lm][16 + lg * 4] = pbv;
        }

        // ---- O^T += V^T * P^T (per-wave Pb; in-order wave DS, no barrier) ----
        #pragma unroll
        for (int jt = 0; jt < 4; ++jt) {
            f16x8 pf = *(const f16x8*)&Pb[w][jt * 16 + lm][lg * 8];
            #pragma unroll
            for (int dt = 0; dt < 2; ++dt) {
                f32x4 c = {Oacc[dt][jt][0], Oacc[dt][jt][1], Oacc[dt][jt][2], Oacc[dt][jt][3]};
                c = __builtin_amdgcn_mfma_f32_16x16x32_f16(vf[dt], pf, c, 0, 0, 0);
                Oacc[dt][jt][0] = c[0]; Oacc[dt][jt][1] = c[1];
                Oacc[dt][jt][2] = c[2]; Oacc[dt][jt][3] = c[3];
            }
        }
    }

    // ---- epilogue: col j = lm-local; rows d = dt*16+lg*4+rr; float4 I/O ----
    #pragma unroll
    for (int jt = 0; jt < 4; ++jt) {
        const int j = j0w + jt * 16 + lm;
        const float inv = 1.0f / lrow[jt];
        #pragma unroll
        for (int dt = 0; dt < 2; ++dt) {
            const float* gp = g + base + (size_t)j * 128 + dt * 16 + lg * 4;
            float4 gv = *(const float4*)gp;
            float4 ov;
            ov.x = Oacc[dt][jt][0] * inv * gv.x;
            ov.y = Oacc[dt][jt][1] * inv * gv.y;
            ov.z = Oacc[dt][jt][2] * inv * gv.z;
            ov.w = Oacc[dt][jt][3] * inv * gv.w;
            *(float4*)(go + base + (size_t)j * 128 + dt * 16 + lg * 4) = ov;
        }
    }
}

// ---------------------------------------------------------------------------
// Kernel C: out = go @ Wo + bo.  (unchanged; not the bottleneck yet)
// ---------------------------------------------------------------------------
__global__ __launch_bounds__(256) void out_proj_kernel(
    const float* __restrict__ go, const float* __restrict__ Wo, const float* __restrict__ bo,
    float* __restrict__ out)
{
    __shared__ float at[64][140];
    const int tid = threadIdx.x;
    const int p0  = blockIdx.x * 64;

    for (int i = tid; i < 64 * 32; i += 256) {
        int row = i >> 5, c4 = (i & 31) * 4;
        float4 val = *(const float4*)(go + (size_t)(p0 + row) * 128 + c4);
        at[row][c4 + 0] = val.x; at[row][c4 + 1] = val.y;
        at[row][c4 + 2] = val.z; at[row][c4 + 3] = val.w;
    }
    __syncthreads();

    const int ty = tid >> 4, tx = tid & 15;
    float acc[4][8] = {};
    #pragma unroll 2
    for (int kk = 0; kk < 128; ++kk) {
        float4 wA = *(const float4*)(Wo + kk * 128 + tx * 8);
        float4 wB = *(const float4*)(Wo + kk * 128 + tx * 8 + 4);
        #pragma unroll
        for (int rr = 0; rr < 4; ++rr) {
            float av = at[ty * 4 + rr][kk];
            acc[rr][0] = fmaf(av, wA.x, acc[rr][0]);
            acc[rr][1] = fmaf(av, wA.y, acc[rr][1]);
            acc[rr][2] = fmaf(av, wA.z, acc[rr][2]);
            acc[rr][3] = fmaf(av, wA.w, acc[rr][3]);
            acc[rr][4] = fmaf(av, wB.x, acc[rr][4]);
            acc[rr][5] = fmaf(av, wB.y, acc[rr][5]);
            acc[rr][6] = fmaf(av, wB.z, acc[rr][6]);
            acc[rr][7] = fmaf(av, wB.w, acc[rr][7]);
        }
    }
    #pragma unroll
    for (int rr = 0; rr < 4; ++rr) {
        float ov[8];
        #pragma unroll
        for (int c = 0; c < 8; ++c) ov[c] = acc[rr][c] + bo[tx * 8 + c];
        float* outp = out + (size_t)(p0 + ty * 4 + rr) * 128 + tx * 8;
        *(float4*)outp       = *(float4*)ov;
        *(float4*)(outp + 4) = *(float4*)(ov + 4);
    }
}

// ---------------------------------------------------------------------------
extern "C" void kernel_launch(void* const* d_in, const int* in_sizes, int n_in,
                              void* d_out, int out_size, void* d_ws, size_t ws_size,
                              hipStream_t stream) {
    const float* pair = (const float*)d_in[0];
    const float* ln_w = (const float*)d_in[1];
    const float* ln_b = (const float*)d_in[2];
    const float* Wq   = (const float*)d_in[3];
    const float* Wk   = (const float*)d_in[4];
    const float* Wv   = (const float*)d_in[5];
    const float* Wb   = (const float*)d_in[6];
    const float* Wg   = (const float*)d_in[7];
    const float* bg   = (const float*)d_in[8];
    const float* Wo   = (const float*)d_in[9];
    const float* bo   = (const float*)d_in[10];

    // workspace layout (floats): q,k,v,g,go = 65536*128 each; bias_n = 4*65536
    float* ws     = (float*)d_ws;
    float* q      = ws;
    float* k      = ws + (size_t)1 * NPOS * 128;
    float* v      = ws + (size_t)2 * NPOS * 128;
    float* g      = ws + (size_t)3 * NPOS * 128;
    float* go     = ws + (size_t)4 * NPOS * 128;
    float* bias_n = ws + (size_t)5 * NPOS * 128;
    float* out    = (float*)d_out;

    // Transient scratch for pre-split weights: live only during ln_proj,
    // placed in d_out (out_proj overwrites all of d_out at the end).
    _Float16* Wt_hi = (_Float16*)d_out;
    _Float16* Wt_lo = Wt_hi + (size_t)512 * 128;

    hipLaunchKernelGGL(split_w_kernel, dim3(256), dim3(256), 0, stream,
                       Wq, Wk, Wv, Wg, Wt_hi, Wt_lo);
    hipLaunchKernelGGL(ln_proj_kernel, dim3(1024), dim3(256), 0, stream,
                       pair, ln_w, ln_b, Wb, bg, Wt_hi, Wt_lo, q, k, v, g, bias_n);
    hipLaunchKernelGGL(attn_kernel, dim3(1024), dim3(256), 0, stream,
                       q, k, v, g, bias_n, go);
    hipLaunchKernelGGL(out_proj_kernel, dim3(1024), dim3(256), 0, stream,
                       go, Wo, bo, out);
}

// Round 7
// 255.624 us; speedup vs baseline: 2.1664x; 1.0327x over previous
//
#include <hip/hip_runtime.h>
#include <math.h>

// Sizes (hard-coded per reference): B=1, L=256, D=128, H=4, DH=32
// positions P = L*L = 65536; HD = H*DH = 128
#define NPOS 65536

typedef _Float16 f16x8 __attribute__((ext_vector_type(8)));
typedef _Float16 f16x4 __attribute__((ext_vector_type(4)));
typedef float    f32x4 __attribute__((ext_vector_type(4)));

__device__ __forceinline__ unsigned short f16bits(_Float16 h) {
    return __builtin_bit_cast(unsigned short, h);
}

// ---------------------------------------------------------------------------
// Kernel P: transpose W{q,k,v,g} (fp32 [k=128][n=128]) into f16 hi plane only:
// Wt_hi[n_global=512][k=128]. (W-lo dropped round-7: adds <=3e-5 to out,
// halves ln_proj's B LDS traffic + MFMA count.)
// ---------------------------------------------------------------------------
__global__ __launch_bounds__(256) void split_w_kernel(
    const float* __restrict__ Wq, const float* __restrict__ Wk,
    const float* __restrict__ Wv, const float* __restrict__ Wg,
    _Float16* __restrict__ Wt_hi)
{
    int t = blockIdx.x * 256 + threadIdx.x;       // 0..65535
    int ng = t >> 7, kk = t & 127;
    int mat = ng >> 7, n = ng & 127;
    const float* W = (mat == 0) ? Wq : (mat == 1) ? Wk : (mat == 2) ? Wv : Wg;
    Wt_hi[t] = (_Float16)W[kk * 128 + n];
}

// ---------------------------------------------------------------------------
// Kernel A (round-7): LN + split-f16(A-side only) MFMA GEMM.
// Outputs now f16: q as hi/lo planes (scale folded), k/v/g hi-only.
// Round-6 evidence (75us, Mfma 13%, VALU 15%, LDS ~68% busy): B-frag
// ds_read_b128 traffic (hi+lo) dominated. Fixes: single B plane (W-lo
// dropped), 2-barrier/chunk pipeline (prev-chunk store overlaps next B load),
// f16 outputs halve store traffic. LDS 34.8KB -> 4 blocks/CU.
// ---------------------------------------------------------------------------
__global__ __launch_bounds__(256, 4) void ln_proj_kernel(
    const float* __restrict__ pair, const float* __restrict__ ln_w, const float* __restrict__ ln_b,
    const float* __restrict__ Wb, const float* __restrict__ bg,
    const _Float16* __restrict__ Wt_hi,
    _Float16* __restrict__ q_hi, _Float16* __restrict__ q_lo,
    _Float16* __restrict__ k16, _Float16* __restrict__ v16, _Float16* __restrict__ g16,
    float* __restrict__ bias_n)
{
    __shared__ _Float16 xbuf[2][64][136];   // [0]: xh then Bh; [1]: xl then stg(u32[64][68])
    _Float16 (*xh)[136] = xbuf[0];
    _Float16 (*xl)[136] = xbuf[1];

    const int tid = threadIdx.x;
    const int p0  = blockIdx.x * 64;
    const int r   = tid >> 2;          // row 0..63
    const int cb  = (tid & 3) * 32;    // col base (4 threads/row)

    // ---- load 32 pair values (float4) ----
    float xv[32];
    {
        const float4* pr = (const float4*)(pair + (size_t)(p0 + r) * 128 + cb);
        #pragma unroll
        for (int i = 0; i < 8; ++i) {
            float4 t = pr[i];
            xv[i * 4 + 0] = t.x; xv[i * 4 + 1] = t.y;
            xv[i * 4 + 2] = t.z; xv[i * 4 + 3] = t.w;
        }
    }
    // ---- LN stats across the 4 threads of the row ----
    float sum = 0.f, sq = 0.f;
    #pragma unroll
    for (int i = 0; i < 32; ++i) { sum += xv[i]; sq += xv[i] * xv[i]; }
    sum += __shfl_xor(sum, 1); sq += __shfl_xor(sq, 1);
    sum += __shfl_xor(sum, 2); sq += __shfl_xor(sq, 2);
    float mean = sum * (1.f / 128.f);
    float var  = sq * (1.f / 128.f) - mean * mean;
    float rstd = rsqrtf(var + 1e-5f);

    // ---- normalize, split to f16 hi/lo, store to LDS; bias partial dots ----
    float b0 = 0.f, b1 = 0.f, b2 = 0.f, b3 = 0.f;
    #pragma unroll
    for (int i8 = 0; i8 < 4; ++i8) {
        float4 lw0 = *(const float4*)(ln_w + cb + i8 * 8);
        float4 lw1 = *(const float4*)(ln_w + cb + i8 * 8 + 4);
        float4 lb0 = *(const float4*)(ln_b + cb + i8 * 8);
        float4 lb1 = *(const float4*)(ln_b + cb + i8 * 8 + 4);
        float lw[8] = {lw0.x, lw0.y, lw0.z, lw0.w, lw1.x, lw1.y, lw1.z, lw1.w};
        float lb[8] = {lb0.x, lb0.y, lb0.z, lb0.w, lb1.x, lb1.y, lb1.z, lb1.w};
        f16x8 hv, lv;
        #pragma unroll
        for (int j = 0; j < 8; ++j) {
            int i = i8 * 8 + j;
            float xn = (xv[i] - mean) * rstd * lw[j] + lb[j];
            _Float16 h = (_Float16)xn;
            hv[j] = h;
            lv[j] = (_Float16)((xn - (float)h) * 2048.0f);
            float4 wb = *(const float4*)(Wb + (size_t)(cb + i) * 4);
            b0 = fmaf(xn, wb.x, b0); b1 = fmaf(xn, wb.y, b1);
            b2 = fmaf(xn, wb.z, b2); b3 = fmaf(xn, wb.w, b3);
        }
        *(f16x8*)&xh[r][cb + i8 * 8] = hv;
        *(f16x8*)&xl[r][cb + i8 * 8] = lv;
    }
    // reduce bias dots across the 4 threads of the row, store natural layout
    b0 += __shfl_xor(b0, 1); b1 += __shfl_xor(b1, 1);
    b2 += __shfl_xor(b2, 1); b3 += __shfl_xor(b3, 1);
    b0 += __shfl_xor(b0, 2); b1 += __shfl_xor(b1, 2);
    b2 += __shfl_xor(b2, 2); b3 += __shfl_xor(b3, 2);
    if ((tid & 3) == 0) {
        int p = p0 + r;                        // p = j*256 + kpos
        bias_n[0 * NPOS + p] = b0;
        bias_n[1 * NPOS + p] = b1;
        bias_n[2 * NPOS + p] = b2;
        bias_n[3 * NPOS + p] = b3;
    }
    __syncthreads();

    // ---- A fragments -> registers (16 rows per wave, full K=128) ----
    const int w  = tid >> 6, l = tid & 63;
    const int lm = l & 15, lg = l >> 4;
    const int arow = w * 16 + lm;

    f16x8 ahf[4], alf[4];
    #pragma unroll
    for (int kt = 0; kt < 4; ++kt) {
        ahf[kt] = *(const f16x8*)&xh[arow][kt * 32 + lg * 8];
        alf[kt] = *(const f16x8*)&xl[arow][kt * 32 + lg * 8];
    }

    _Float16 (*Bh)[136] = xbuf[0];                 // B chunk (single plane)
    unsigned* stg = (unsigned*)&xbuf[1][0][0];     // u32 [64][68] (hi | lo<<16)

    const float scale = 0.17677669529663687f;      // 1/sqrt(32)

    for (int chunk = 0; chunk < 8; ++chunk) {
        __syncthreads();   // stg(chunk-1) writes visible; Bh frag-reads done

        // issue B-chunk global loads (4 x 16B per thread)
        const _Float16* srch = Wt_hi + (size_t)(chunk * 64) * 128;
        f16x8 breg[4];
        #pragma unroll
        for (int it = 0; it < 4; ++it) {
            int idx = it * 256 + tid;
            breg[it] = *(const f16x8*)(srch + (idx >> 4) * 128 + (idx & 15) * 8);
        }

        // store previous chunk's outputs from stg (overlaps B-load latency)
        if (chunk > 0) {
            const int pm = (chunk - 1) >> 1, pcol = ((chunk - 1) & 1) * 64;
            #pragma unroll
            for (int it = 0; it < 4; ++it) {
                int idx = it * 256 + tid;
                int row = idx >> 4, c4 = (idx & 15) * 4;
                uint4 pk = *(const uint4*)&stg[row * 68 + c4];
                ushort4 hv = make_ushort4((unsigned short)(pk.x & 0xffff),
                                          (unsigned short)(pk.y & 0xffff),
                                          (unsigned short)(pk.z & 0xffff),
                                          (unsigned short)(pk.w & 0xffff));
                size_t off = (size_t)(p0 + row) * 128 + pcol + c4;
                if (pm == 0) {
                    *(ushort4*)(q_hi + off) = hv;
                    ushort4 lv = make_ushort4((unsigned short)(pk.x >> 16),
                                              (unsigned short)(pk.y >> 16),
                                              (unsigned short)(pk.z >> 16),
                                              (unsigned short)(pk.w >> 16));
                    *(ushort4*)(q_lo + off) = lv;
                } else if (pm == 1) *(ushort4*)(k16 + off) = hv;
                else if   (pm == 2) *(ushort4*)(v16 + off) = hv;
                else                *(ushort4*)(g16 + off) = hv;
            }
        }

        // write B chunk to LDS
        #pragma unroll
        for (int it = 0; it < 4; ++it) {
            int idx = it * 256 + tid;
            *(f16x8*)&Bh[idx >> 4][(idx & 15) * 8] = breg[it];
        }
        __syncthreads();   // B ready; stg free for rewrite

        // ---- MFMA: 4 col-tiles x 4 kt x 2 (x-split only) ----
        const int mat = chunk >> 1;
        f32x4 acch[4], accc[4];
        #pragma unroll
        for (int ct = 0; ct < 4; ++ct) {
            acch[ct] = (f32x4){0.f, 0.f, 0.f, 0.f};
            accc[ct] = (f32x4){0.f, 0.f, 0.f, 0.f};
        }
        #pragma unroll
        for (int kt = 0; kt < 4; ++kt) {
            const int koff = kt * 32 + lg * 8;
            #pragma unroll
            for (int ct = 0; ct < 4; ++ct) {
                f16x8 bh = *(const f16x8*)&Bh[ct * 16 + lm][koff];
                acch[ct] = __builtin_amdgcn_mfma_f32_16x16x32_f16(ahf[kt], bh, acch[ct], 0, 0, 0);
                accc[ct] = __builtin_amdgcn_mfma_f32_16x16x32_f16(alf[kt], bh, accc[ct], 0, 0, 0);
            }
        }

        // ---- epilogue math -> stg (packed u32) ----
        const int colhalf = (chunk & 1) * 64;
        #pragma unroll
        for (int ct = 0; ct < 4; ++ct) {
            const int col = ct * 16 + lm;
            float bgv = (mat == 3) ? bg[colhalf + col] : 0.f;
            #pragma unroll
            for (int rr = 0; rr < 4; ++rr) {
                float val = acch[ct][rr] + accc[ct][rr] * (1.0f / 2048.0f);
                if (mat == 0) val *= scale;
                if (mat == 3) val = 1.f / (1.f + __expf(-(val + bgv)));
                _Float16 h = (_Float16)val;
                unsigned pk = f16bits(h);
                if (mat == 0) {
                    _Float16 lo = (_Float16)((val - (float)h) * 2048.0f);
                    pk |= ((unsigned)f16bits(lo)) << 16;
                }
                stg[(w * 16 + lg * 4 + rr) * 68 + col] = pk;
            }
        }
    }

    // ---- final chunk store ----
    __syncthreads();
    {
        #pragma unroll
        for (int it = 0; it < 4; ++it) {
            int idx = it * 256 + tid;
            int row = idx >> 4, c4 = (idx & 15) * 4;
            uint4 pk = *(const uint4*)&stg[row * 68 + c4];
            ushort4 hv = make_ushort4((unsigned short)(pk.x & 0xffff),
                                      (unsigned short)(pk.y & 0xffff),
                                      (unsigned short)(pk.z & 0xffff),
                                      (unsigned short)(pk.w & 0xffff));
            *(ushort4*)(g16 + (size_t)(p0 + row) * 128 + 64 + c4) = hv;
        }
    }
}

// ---------------------------------------------------------------------------
// Kernel B (round-7): S^T-form MFMA flash attention, 64-kpos phases.
// Round-6 residual (~73us, latency/barrier-bound): 16 barriers + per-chunk
// softmax chains. Changes: 64-kpos staging phases (8 barriers total), q read
// pre-split f16 (no conversion), k/v plain f16 (K-lo term dropped: +2.5e-5
// on scores), conflict-free LDS pitches (44/76), one softmax round per 64
// kpos (16 scores/lane + 2 shuffles). LDS 49.4KB, 3 blocks/CU.
// ---------------------------------------------------------------------------
__global__ __launch_bounds__(256, 3) void attn_kernel(
    const _Float16* __restrict__ q_hi, const _Float16* __restrict__ q_lo,
    const _Float16* __restrict__ k16, const _Float16* __restrict__ v16,
    const _Float16* __restrict__ g16, const float* __restrict__ bias_n,
    float* __restrict__ go)
{
    __shared__ _Float16 Khs[64][44];
    __shared__ _Float16 Vts[32][76];     // V^T: [d][kpos_local 0..63]
    __shared__ _Float16 Pb[4][64][76];   // per-wave P[j][kpos_local] f16

    const int tid  = threadIdx.x;
    const int w    = tid >> 6;
    const int lane = tid & 63;
    const int lg   = lane >> 4, lm = lane & 15;
    const int i = blockIdx.x >> 2, h = blockIdx.x & 3;
    const size_t base = (size_t)i * 256 * 128 + (size_t)h * 32;
    const int j0w = w * 64;

    // Q fragments: direct f16x8 loads from pre-split planes
    f16x8 qh[4], ql[4];
    #pragma unroll
    for (int jt = 0; jt < 4; ++jt) {
        size_t off = base + (size_t)(j0w + jt * 16 + lm) * 128 + lg * 8;
        qh[jt] = *(const f16x8*)(q_hi + off);
        ql[jt] = *(const f16x8*)(q_lo + off);
    }

    float Oacc[2][4][4] = {};            // [dt][jt][rr]: O^T (col=j=lm, row=d)
    float mrow[4], lrow[4];
    #pragma unroll
    for (int jt = 0; jt < 4; ++jt) { mrow[jt] = -1e30f; lrow[jt] = 0.f; }

    const int sr  = tid >> 2;            // staging kpos-local 0..63
    const int sc8 = (tid & 3) * 8;       // staging d col (8-wide)

    f16x8 kpre = *(const f16x8*)(k16 + base + (size_t)sr * 128 + sc8);
    f16x8 vpre = *(const f16x8*)(v16 + base + (size_t)sr * 128 + sc8);

    for (int kc = 0; kc < 256; kc += 64) {
        __syncthreads();
        *(f16x8*)&Khs[sr][sc8] = kpre;
        #pragma unroll
        for (int e = 0; e < 8; ++e) Vts[sc8 + e][sr] = vpre[e];
        __syncthreads();
        if (kc + 64 < 256) {             // prefetch next phase
            kpre = *(const f16x8*)(k16 + base + (size_t)(kc + 64 + sr) * 128 + sc8);
            vpre = *(const f16x8*)(v16 + base + (size_t)(kc + 64 + sr) * 128 + sc8);
        }

        // A-operand frags: K rows t*16+lm (kpos), V^T rows dt*16+lm (d)
        f16x8 kf[4];
        #pragma unroll
        for (int t = 0; t < 4; ++t) kf[t] = *(const f16x8*)&Khs[t * 16 + lm][lg * 8];
        f16x8 vf[2][2];
        #pragma unroll
        for (int dt = 0; dt < 2; ++dt)
            #pragma unroll
            for (int ks = 0; ks < 2; ++ks)
                vf[dt][ks] = *(const f16x8*)&Vts[dt * 16 + lm][ks * 32 + lg * 8];

        // ---- per j-tile: S^T (4 sub-tiles), softmax over 16 reg scores ----
        #pragma unroll
        for (int jt = 0; jt < 4; ++jt) {
            const float* bj = bias_n + (size_t)h * NPOS
                            + (size_t)(j0w + jt * 16 + lm) * 256 + kc + lg * 4;
            float s[16];
            #pragma unroll
            for (int t = 0; t < 4; ++t) {
                float4 bv = *(const float4*)(bj + t * 16);
                f32x4 c  = {bv.x, bv.y, bv.z, bv.w};
                f32x4 cl = {0.f, 0.f, 0.f, 0.f};
                c  = __builtin_amdgcn_mfma_f32_16x16x32_f16(kf[t], qh[jt], c,  0, 0, 0);
                cl = __builtin_amdgcn_mfma_f32_16x16x32_f16(kf[t], ql[jt], cl, 0, 0, 0);
                #pragma unroll
                for (int rr = 0; rr < 4; ++rr)
                    s[t * 4 + rr] = c[rr] + cl[rr] * (1.0f / 2048.0f);
            }
            float mx = s[0];
            #pragma unroll
            for (int e = 1; e < 16; ++e) mx = fmaxf(mx, s[e]);
            mx = fmaxf(mx, __shfl_xor(mx, 16));
            mx = fmaxf(mx, __shfl_xor(mx, 32));
            float mn = fmaxf(mrow[jt], mx);
            float alpha = __expf(mrow[jt] - mn);
            mrow[jt] = mn;
            float ps = 0.f;
            #pragma unroll
            for (int e = 0; e < 16; ++e) { s[e] = __expf(s[e] - mn); ps += s[e]; }
            ps += __shfl_xor(ps, 16);
            ps += __shfl_xor(ps, 32);
            lrow[jt] = lrow[jt] * alpha + ps;
            #pragma unroll
            for (int dt = 0; dt < 2; ++dt)
                #pragma unroll
                for (int rr = 0; rr < 4; ++rr) Oacc[dt][jt][rr] *= alpha;
            #pragma unroll
            for (int t = 0; t < 4; ++t) {
                f16x4 pv;
                #pragma unroll
                for (int rr = 0; rr < 4; ++rr) pv[rr] = (_Float16)s[t * 4 + rr];
                *(f16x4*)&Pb[w][jt * 16 + lm][t * 16 + lg * 4] = pv;
            }
        }

        // ---- O^T += V^T * P^T (per-wave Pb; wave DS in-order, no barrier) ----
        #pragma unroll
        for (int jt = 0; jt < 4; ++jt) {
            f16x8 pf0 = *(const f16x8*)&Pb[w][jt * 16 + lm][lg * 8];
            f16x8 pf1 = *(const f16x8*)&Pb[w][jt * 16 + lm][32 + lg * 8];
            #pragma unroll
            for (int dt = 0; dt < 2; ++dt) {
                f32x4 c = {Oacc[dt][jt][0], Oacc[dt][jt][1], Oacc[dt][jt][2], Oacc[dt][jt][3]};
                c = __builtin_amdgcn_mfma_f32_16x16x32_f16(vf[dt][0], pf0, c, 0, 0, 0);
                c = __builtin_amdgcn_mfma_f32_16x16x32_f16(vf[dt][1], pf1, c, 0, 0, 0);
                Oacc[dt][jt][0] = c[0]; Oacc[dt][jt][1] = c[1];
                Oacc[dt][jt][2] = c[2]; Oacc[dt][jt][3] = c[3];
            }
        }
    }

    // ---- epilogue: normalize, gate (f16), store go f32 ----
    #pragma unroll
    for (int jt = 0; jt < 4; ++jt) {
        const int j = j0w + jt * 16 + lm;
        const float inv = 1.0f / lrow[jt];
        #pragma unroll
        for (int dt = 0; dt < 2; ++dt) {
            f16x4 gv4 = *(const f16x4*)(g16 + base + (size_t)j * 128 + dt * 16 + lg * 4);
            float4 ov;
            ov.x = Oacc[dt][jt][0] * inv * (float)gv4[0];
            ov.y = Oacc[dt][jt][1] * inv * (float)gv4[1];
            ov.z = Oacc[dt][jt][2] * inv * (float)gv4[2];
            ov.w = Oacc[dt][jt][3] * inv * (float)gv4[3];
            *(float4*)(go + base + (size_t)j * 128 + dt * 16 + lg * 4) = ov;
        }
    }
}

// ---------------------------------------------------------------------------
// Kernel C: out = go @ Wo + bo.  (unchanged)
// ---------------------------------------------------------------------------
__global__ __launch_bounds__(256) void out_proj_kernel(
    const float* __restrict__ go, const float* __restrict__ Wo, const float* __restrict__ bo,
    float* __restrict__ out)
{
    __shared__ float at[64][140];
    const int tid = threadIdx.x;
    const int p0  = blockIdx.x * 64;

    for (int i = tid; i < 64 * 32; i += 256) {
        int row = i >> 5, c4 = (i & 31) * 4;
        float4 val = *(const float4*)(go + (size_t)(p0 + row) * 128 + c4);
        at[row][c4 + 0] = val.x; at[row][c4 + 1] = val.y;
        at[row][c4 + 2] = val.z; at[row][c4 + 3] = val.w;
    }
    __syncthreads();

    const int ty = tid >> 4, tx = tid & 15;
    float acc[4][8] = {};
    #pragma unroll 2
    for (int kk = 0; kk < 128; ++kk) {
        float4 wA = *(const float4*)(Wo + kk * 128 + tx * 8);
        float4 wB = *(const float4*)(Wo + kk * 128 + tx * 8 + 4);
        #pragma unroll
        for (int rr = 0; rr < 4; ++rr) {
            float av = at[ty * 4 + rr][kk];
            acc[rr][0] = fmaf(av, wA.x, acc[rr][0]);
            acc[rr][1] = fmaf(av, wA.y, acc[rr][1]);
            acc[rr][2] = fmaf(av, wA.z, acc[rr][2]);
            acc[rr][3] = fmaf(av, wA.w, acc[rr][3]);
            acc[rr][4] = fmaf(av, wB.x, acc[rr][4]);
            acc[rr][5] = fmaf(av, wB.y, acc[rr][5]);
            acc[rr][6] = fmaf(av, wB.z, acc[rr][6]);
            acc[rr][7] = fmaf(av, wB.w, acc[rr][7]);
        }
    }
    #pragma unroll
    for (int rr = 0; rr < 4; ++rr) {
        float ov[8];
        #pragma unroll
        for (int c = 0; c < 8; ++c) ov[c] = acc[rr][c] + bo[tx * 8 + c];
        float* outp = out + (size_t)(p0 + ty * 4 + rr) * 128 + tx * 8;
        *(float4*)outp       = *(float4*)ov;
        *(float4*)(outp + 4) = *(float4*)(ov + 4);
    }
}

// ---------------------------------------------------------------------------
extern "C" void kernel_launch(void* const* d_in, const int* in_sizes, int n_in,
                              void* d_out, int out_size, void* d_ws, size_t ws_size,
                              hipStream_t stream) {
    const float* pair = (const float*)d_in[0];
    const float* ln_w = (const float*)d_in[1];
    const float* ln_b = (const float*)d_in[2];
    const float* Wq   = (const float*)d_in[3];
    const float* Wk   = (const float*)d_in[4];
    const float* Wv   = (const float*)d_in[5];
    const float* Wb   = (const float*)d_in[6];
    const float* Wg   = (const float*)d_in[7];
    const float* bg   = (const float*)d_in[8];
    const float* Wo   = (const float*)d_in[9];
    const float* bo   = (const float*)d_in[10];

    // workspace: f16 planes q_hi,q_lo,k,v,g (NPOS*128 each) + go f32 + bias_n
    _Float16* q_hi = (_Float16*)d_ws;
    _Float16* q_lo = q_hi + (size_t)NPOS * 128;
    _Float16* k16  = q_lo + (size_t)NPOS * 128;
    _Float16* v16  = k16 + (size_t)NPOS * 128;
    _Float16* g16  = v16 + (size_t)NPOS * 128;
    float* go      = (float*)(g16 + (size_t)NPOS * 128);
    float* bias_n  = go + (size_t)NPOS * 128;
    float* out     = (float*)d_out;

    // Transient scratch for transposed hi-plane weights: in d_out
    // (out_proj overwrites all of d_out at the end).
    _Float16* Wt_hi = (_Float16*)d_out;

    hipLaunchKernelGGL(split_w_kernel, dim3(256), dim3(256), 0, stream,
                       Wq, Wk, Wv, Wg, Wt_hi);
    hipLaunchKernelGGL(ln_proj_kernel, dim3(1024), dim3(256), 0, stream,
                       pair, ln_w, ln_b, Wb, bg, Wt_hi,
                       q_hi, q_lo, k16, v16, g16, bias_n);
    hipLaunchKernelGGL(attn_kernel, dim3(1024), dim3(256), 0, stream,
                       q_hi, q_lo, k16, v16, g16, bias_n, go);
    hipLaunchKernelGGL(out_proj_kernel, dim3(1024), dim3(256), 0, stream,
                       go, Wo, bo, out);
}